// Round 3
// baseline (524.176 us; speedup 1.0000x reference)
//
#include <hip/hip_runtime.h>
#include <math.h>

// ---------------------------------------------------------------------------
// Problem constants
// ---------------------------------------------------------------------------
#define BATCH 16
#define CH    256          // channels C
#define NT    1024         // tokens n = 32*32
#define NH    8            // heads
#define DH    32           // dim_head
#define HID   1024         // ffn hidden
#define MROWS (BATCH * NT) // 16384 rows for all GEMMs
#define LN_EPS 1e-5f

typedef unsigned short u16;
typedef __attribute__((ext_vector_type(8))) short short8;  // 8 x bf16 (4 VGPRs)
typedef __attribute__((ext_vector_type(4))) float f32x4;

struct __align__(8) US4 { u16 x, y, z, w; };
struct __align__(16) F4 { float x, y, z, w; };

#define MFMA(a, b, c) __builtin_amdgcn_mfma_f32_16x16x32_bf16((a), (b), (c), 0, 0, 0)

__device__ __forceinline__ float bf2f(u16 u) {
  union { unsigned int i; float f; } v; v.i = ((unsigned int)u) << 16; return v.f;
}
__device__ __forceinline__ u16 f2bf(float f) {
  union { float f; unsigned int i; } v; v.f = f;
  unsigned int i = v.i;
  return (u16)((i + 0x7fffu + ((i >> 16) & 1u)) >> 16);  // RNE
}

// ---------------------------------------------------------------------------
// Weight transpose + fp32->bf16: in (K x N) fp32 -> out (N x K) bf16
// grid: (K/64, N/64), block 256
// tl is indexed [K-local][N-local] in BOTH phases (round-2 bug: read phase
// had the indices swapped -> block-swap without intra-block transpose).
// ---------------------------------------------------------------------------
__global__ __launch_bounds__(256) void k_transpose(const float* __restrict__ in,
                                                   u16* __restrict__ out,
                                                   int K, int N) {
  __shared__ u16 tl[64][66];
  const int t = threadIdx.x;
  const int kb = blockIdx.x * 64, nb = blockIdx.y * 64;
#pragma unroll
  for (int it = 0; it < 16; ++it) {
    int n_l = t & 63, k_l = it * 4 + (t >> 6);
    tl[k_l][n_l] = f2bf(in[(size_t)(kb + k_l) * N + nb + n_l]);
  }
  __syncthreads();
#pragma unroll
  for (int it = 0; it < 16; ++it) {
    int k_l = t & 63, n_l = it * 4 + (t >> 6);
    out[(size_t)(nb + n_l) * K + kb + k_l] = tl[k_l][n_l];  // FIX: [k][n]
  }
}

// ---------------------------------------------------------------------------
// Bias pre-gather into transposed layout: biasT[h][j][i] = table[rel[i*NT+j]][h]
// grid: 256 (16 jb x 16 ib), block 256
// ---------------------------------------------------------------------------
__global__ __launch_bounds__(256) void k_prep_bias(const float* __restrict__ table,
                                                   const int* __restrict__ rel,
                                                   u16* __restrict__ biasT) {
  __shared__ u16 tl[64][66];
  const int t = threadIdx.x;
  const int jb = (blockIdx.x & 15) * 64, ib = (blockIdx.x >> 4) * 64;
  int idxs[16];
#pragma unroll
  for (int it = 0; it < 16; ++it) {
    int j_l = t & 63, i_l = it * 4 + (t >> 6);
    idxs[it] = rel[(size_t)(ib + i_l) * NT + jb + j_l];
  }
  for (int h = 0; h < NH; ++h) {
    __syncthreads();
#pragma unroll
    for (int it = 0; it < 16; ++it) {
      int j_l = t & 63, i_l = it * 4 + (t >> 6);
      tl[j_l][i_l] = f2bf(table[(size_t)idxs[it] * NH + h]);
    }
    __syncthreads();
#pragma unroll
    for (int it = 0; it < 16; ++it) {
      int i_l = t & 63, j_l = it * 4 + (t >> 6);
      biasT[((size_t)(h << 10) + jb + j_l) * NT + ib + i_l] = tl[j_l][i_l];
    }
  }
}

// ---------------------------------------------------------------------------
// LN1 fused with (B,C,n) -> (B,n,C) transpose + fp32->bf16.
// grid: BATCH*16 (64 positions per block), block 256
// ---------------------------------------------------------------------------
__global__ __launch_bounds__(256) void k_ln1(const float* __restrict__ x,
                                             const float* __restrict__ w,
                                             const float* __restrict__ b,
                                             u16* __restrict__ x1) {
  __shared__ u16 tile[CH][68];  // stride 68 u16 = 136 B (8B-aligned rows)
  __shared__ float red_s[4][64], red_q[4][64], mu_s[64], rs_s[64];
  const int t = threadIdx.x;
  const int bb = blockIdx.x >> 4, pb = blockIdx.x & 15;
  const int pos0 = pb * 64;
  // phase 1: coalesced float4 load (4 fp32 along pos per thread) -> bf16 tile
#pragma unroll
  for (int it = 0; it < 16; ++it) {
    int c = it * 16 + (t >> 4), p4 = (t & 15) * 4;
    F4 v = *(const F4*)(x + ((size_t)bb * CH + c) * NT + pos0 + p4);
    US4 o; o.x = f2bf(v.x); o.y = f2bf(v.y); o.z = f2bf(v.z); o.w = f2bf(v.w);
    *(US4*)&tile[c][p4] = o;
  }
  __syncthreads();
  // phase 2: partial mean/var per position (over bf16-rounded values)
  {
    int pos = t & 63, g = t >> 6;
    float s = 0.f, q = 0.f;
#pragma unroll 8
    for (int cc = 0; cc < 64; ++cc) {
      float v = bf2f(tile[g * 64 + cc][pos]);
      s += v; q += v * v;
    }
    red_s[g][pos] = s; red_q[g][pos] = q;
  }
  __syncthreads();
  if (t < 64) {
    float s = red_s[0][t] + red_s[1][t] + red_s[2][t] + red_s[3][t];
    float q = red_q[0][t] + red_q[1][t] + red_q[2][t] + red_q[3][t];
    float mu = s * (1.f / CH);
    float var = q * (1.f / CH) - mu * mu;
    mu_s[t] = mu;
    rs_s[t] = rsqrtf(fmaxf(var, 0.f) + LN_EPS);
  }
  __syncthreads();
  // phase 3: normalize + write (B,n,C) bf16, coalesced over c
  {
    const int c = t;
    const float wv = w[c], bv = b[c];
    for (int pos = 0; pos < 64; ++pos) {
      float v = (bf2f(tile[c][pos]) - mu_s[pos]) * rs_s[pos] * wv + bv;
      x1[((size_t)bb * NT + pos0 + pos) * CH + c] = f2bf(v);
    }
  }
}

// ---------------------------------------------------------------------------
// MFMA GEMM core: C[64x64 per block] = A(MxK) @ Bt(NxK)^T, 4 waves x (16x64)
// ---------------------------------------------------------------------------
template <int K>
__device__ __forceinline__ void gemm_core(const u16* __restrict__ A,
                                          const u16* __restrict__ Bt,
                                          int r0, int c0, f32x4 acc[4]) {
  const int lane = threadIdx.x & 63;
  const int l16 = lane & 15, quad = lane >> 4;
  const u16* ap = A + (size_t)(r0 + l16) * K + quad * 8;
  const u16* bp = Bt + (size_t)(c0 + l16) * K + quad * 8;
#pragma unroll 8
  for (int k0 = 0; k0 < K; k0 += 32) {
    short8 a = *(const short8*)(ap + k0);
#pragma unroll
    for (int j = 0; j < 4; ++j) {
      short8 bfr = *(const short8*)(bp + (size_t)j * 16 * K + k0);
      acc[j] = MFMA(a, bfr, acc[j]);
    }
  }
}

// QKV: x1(16384x256) @ qkv_wT -> scatter to q/k/v (B,H,n,d) bf16
__global__ __launch_bounds__(256) void k_gemm_qkv(const u16* __restrict__ x1,
                                                  const u16* __restrict__ wT,
                                                  u16* __restrict__ q,
                                                  u16* __restrict__ k,
                                                  u16* __restrict__ v) {
  const int wave = threadIdx.x >> 6, lane = threadIdx.x & 63;
  const int l16 = lane & 15, quad = lane >> 4;
  const int r0 = blockIdx.x * 64 + wave * 16, c0 = blockIdx.y * 64;
  f32x4 acc[4];
#pragma unroll
  for (int j = 0; j < 4; ++j) acc[j] = 0.f;
  gemm_core<CH>(x1, wT, r0, c0, acc);
#pragma unroll
  for (int j = 0; j < 4; ++j) {
    int col = c0 + j * 16 + l16;
    int which = col >> 8, rem = col & 255, h = rem >> 5, dd = rem & 31;
    u16* dst = (which == 0) ? q : (which == 1) ? k : v;
#pragma unroll
    for (int r = 0; r < 4; ++r) {
      int row = r0 + quad * 4 + r;
      int bb = row >> 10, pos = row & 1023;
      dst[(((size_t)bb * NH + h) * NT + pos) * DH + dd] = f2bf(acc[j][r]);
    }
  }
}

// PROJ: attn_out(16384x256) @ proj_wT + proj_b + x^T -> x3 (B,n,C) bf16
__global__ __launch_bounds__(256) void k_gemm_proj(const u16* __restrict__ ao,
                                                   const u16* __restrict__ wT,
                                                   const float* __restrict__ pb,
                                                   const float* __restrict__ x,
                                                   u16* __restrict__ x3) {
  const int wave = threadIdx.x >> 6, lane = threadIdx.x & 63;
  const int l16 = lane & 15, quad = lane >> 4;
  const int r0 = blockIdx.x * 64 + wave * 16, c0 = blockIdx.y * 64;
  f32x4 acc[4];
#pragma unroll
  for (int j = 0; j < 4; ++j) acc[j] = 0.f;
  gemm_core<CH>(ao, wT, r0, c0, acc);
#pragma unroll
  for (int j = 0; j < 4; ++j) {
    int col = c0 + j * 16 + l16;
    float bias = pb[col];
#pragma unroll
    for (int r = 0; r < 4; ++r) {
      int row = r0 + quad * 4 + r;
      int bb = row >> 10, pos = row & 1023;
      float val = acc[j][r] + bias + x[((size_t)bb * CH + col) * NT + pos];
      x3[(size_t)row * CH + col] = f2bf(val);
    }
  }
}

// FFN1: x4ln(16384x256) @ w1T + b1, exact GELU -> ffn_h (16384x1024) bf16
__global__ __launch_bounds__(256) void k_gemm_ffn1(const u16* __restrict__ a,
                                                   const u16* __restrict__ wT,
                                                   const float* __restrict__ b1,
                                                   u16* __restrict__ hmat) {
  const int wave = threadIdx.x >> 6, lane = threadIdx.x & 63;
  const int l16 = lane & 15, quad = lane >> 4;
  const int r0 = blockIdx.x * 64 + wave * 16, c0 = blockIdx.y * 64;
  f32x4 acc[4];
#pragma unroll
  for (int j = 0; j < 4; ++j) acc[j] = 0.f;
  gemm_core<CH>(a, wT, r0, c0, acc);
#pragma unroll
  for (int j = 0; j < 4; ++j) {
    int col = c0 + j * 16 + l16;
    float bias = b1[col];
#pragma unroll
    for (int r = 0; r < 4; ++r) {
      int row = r0 + quad * 4 + r;
      float v = acc[j][r] + bias;
      float g = 0.5f * v * (1.0f + erff(v * 0.70710678118654752f));
      hmat[(size_t)row * HID + col] = f2bf(g);
    }
  }
}

// FFN2: ffn_h(16384x1024) @ w2T + b2 -> x4 (B,n,C) bf16
__global__ __launch_bounds__(256) void k_gemm_ffn2(const u16* __restrict__ a,
                                                   const u16* __restrict__ wT,
                                                   const float* __restrict__ b2,
                                                   u16* __restrict__ x4) {
  const int wave = threadIdx.x >> 6, lane = threadIdx.x & 63;
  const int l16 = lane & 15, quad = lane >> 4;
  const int r0 = blockIdx.x * 64 + wave * 16, c0 = blockIdx.y * 64;
  f32x4 acc[4];
#pragma unroll
  for (int j = 0; j < 4; ++j) acc[j] = 0.f;
  gemm_core<HID>(a, wT, r0, c0, acc);
#pragma unroll
  for (int j = 0; j < 4; ++j) {
    int col = c0 + j * 16 + l16;
    float bias = b2[col];
#pragma unroll
    for (int r = 0; r < 4; ++r) {
      int row = r0 + quad * 4 + r;
      x4[(size_t)row * CH + col] = f2bf(acc[j][r] + bias);
    }
  }
}

// ---------------------------------------------------------------------------
// Flash attention: block = (b,h, 64 q rows); 4 waves x 16 rows.
// K/V staged in 256-row LDS chunks; online softmax; P via LDS round-trip.
// grid: 2048, block 256
// ---------------------------------------------------------------------------
__global__ __launch_bounds__(256) void k_attn(const u16* __restrict__ q,
                                              const u16* __restrict__ k,
                                              const u16* __restrict__ v,
                                              const u16* __restrict__ biasT,
                                              u16* __restrict__ ao) {
  __shared__ u16 Ks[256][40];   // stride 40 elems = 80 B (16B multiple)
  __shared__ u16 Vt[32][264];   // transposed V, stride 264 = 528 B
  __shared__ u16 Ps[4][16][40]; // per-wave P staging
  const int tid = threadIdx.x;
  const int wave = tid >> 6, lane = tid & 63;
  const int quad = lane >> 4, l16 = lane & 15;
  const int bh = blockIdx.x >> 4, qt = blockIdx.x & 15;
  const int h = bh & 7, bb = bh >> 3;
  const int i0 = qt * 64 + wave * 16;
  const float scale = 0.17677669529663687f;  // 1/sqrt(32)
  const float LOG2E = 1.4426950408889634f;

  short8 aq = *(const short8*)(q + ((size_t)bh * NT + i0 + l16) * DH + quad * 8);

  float m_i[4], l_i[4];
  f32x4 acc0 = 0.f, acc1 = 0.f;
#pragma unroll
  for (int r = 0; r < 4; ++r) { m_i[r] = -1e30f; l_i[r] = 0.f; }

  for (int chunk = 0; chunk < 4; ++chunk) {
    __syncthreads();
    const int rbase = chunk * 256;
    const int srow = tid >> 3, sdd = (tid & 7) * 4;
#pragma unroll
    for (int it = 0; it < 8; ++it) {
      int rl = it * 32 + srow;
      US4 kv = *(const US4*)(k + ((size_t)bh * NT + rbase + rl) * DH + sdd);
      *(US4*)&Ks[rl][sdd] = kv;
      US4 vv = *(const US4*)(v + ((size_t)bh * NT + rbase + rl) * DH + sdd);
      Vt[sdd + 0][rl] = vv.x; Vt[sdd + 1][rl] = vv.y;
      Vt[sdd + 2][rl] = vv.z; Vt[sdd + 3][rl] = vv.w;
    }
    __syncthreads();

    for (int j0 = 0; j0 < 256; j0 += 32) {
      short8 bk0 = *(const short8*)&Ks[j0 + l16][quad * 8];
      short8 bk1 = *(const short8*)&Ks[j0 + 16 + l16][quad * 8];
      f32x4 z = 0.f;
      f32x4 s0 = MFMA(aq, bk0, z);
      f32x4 s1 = MFMA(aq, bk1, z);
      const int jg = rbase + j0;
      US4 bb0 = *(const US4*)(biasT + ((size_t)(h << 10) + jg + l16) * NT + i0 + quad * 4);
      US4 bb1 = *(const US4*)(biasT + ((size_t)(h << 10) + jg + 16 + l16) * NT + i0 + quad * 4);
      float p0[4], p1[4];
      p0[0] = s0[0] * scale + bf2f(bb0.x);
      p0[1] = s0[1] * scale + bf2f(bb0.y);
      p0[2] = s0[2] * scale + bf2f(bb0.z);
      p0[3] = s0[3] * scale + bf2f(bb0.w);
      p1[0] = s1[0] * scale + bf2f(bb1.x);
      p1[1] = s1[1] * scale + bf2f(bb1.y);
      p1[2] = s1[2] * scale + bf2f(bb1.z);
      p1[3] = s1[3] * scale + bf2f(bb1.w);
      float tm[4];
#pragma unroll
      for (int r = 0; r < 4; ++r) tm[r] = fmaxf(p0[r], p1[r]);
#pragma unroll
      for (int mask = 1; mask <= 8; mask <<= 1) {
#pragma unroll
        for (int r = 0; r < 4; ++r) tm[r] = fmaxf(tm[r], __shfl_xor(tm[r], mask));
      }
      float sm[4];
#pragma unroll
      for (int r = 0; r < 4; ++r) {
        float mn = fmaxf(m_i[r], tm[r]);
        float al = exp2f((m_i[r] - mn) * LOG2E);
        m_i[r] = mn;
        p0[r] = exp2f((p0[r] - mn) * LOG2E);
        p1[r] = exp2f((p1[r] - mn) * LOG2E);
        sm[r] = p0[r] + p1[r];
        l_i[r] *= al;
        acc0[r] *= al;
        acc1[r] *= al;
      }
#pragma unroll
      for (int mask = 1; mask <= 8; mask <<= 1) {
#pragma unroll
        for (int r = 0; r < 4; ++r) sm[r] += __shfl_xor(sm[r], mask);
      }
#pragma unroll
      for (int r = 0; r < 4; ++r) l_i[r] += sm[r];
#pragma unroll
      for (int r = 0; r < 4; ++r) {
        Ps[wave][quad * 4 + r][l16]      = f2bf(p0[r]);
        Ps[wave][quad * 4 + r][16 + l16] = f2bf(p1[r]);
      }
      // wave-synchronous LDS round-trip (C/D layout -> A layout)
      short8 ap  = *(const short8*)&Ps[wave][l16][quad * 8];
      short8 bv0 = *(const short8*)&Vt[l16][j0 + quad * 8];
      short8 bv1 = *(const short8*)&Vt[16 + l16][j0 + quad * 8];
      acc0 = MFMA(ap, bv0, acc0);
      acc1 = MFMA(ap, bv1, acc1);
    }
  }
#pragma unroll
  for (int r = 0; r < 4; ++r) {
    float inv = 1.0f / l_i[r];
    int row = i0 + quad * 4 + r;
    u16* o = ao + ((size_t)bb * NT + row) * CH + h * DH;
    o[l16]      = f2bf(acc0[r] * inv);
    o[16 + l16] = f2bf(acc1[r] * inv);
  }
}

// ---------------------------------------------------------------------------
// LN2: x3 (B,n,C) bf16 rows contiguous -> x4ln (B,n,C) bf16. One wave per row.
// grid: 4096, block 256
// ---------------------------------------------------------------------------
__global__ __launch_bounds__(256) void k_ln2(const u16* __restrict__ x3,
                                             const float* __restrict__ w,
                                             const float* __restrict__ b,
                                             u16* __restrict__ x4ln) {
  const int wave = threadIdx.x >> 6, lane = threadIdx.x & 63;
  const size_t row = (size_t)blockIdx.x * 4 + wave;
  US4 u = *(const US4*)(x3 + row * CH + lane * 4);
  float v0 = bf2f(u.x), v1 = bf2f(u.y), v2 = bf2f(u.z), v3 = bf2f(u.w);
  float s = v0 + v1 + v2 + v3;
  float qq = v0 * v0 + v1 * v1 + v2 * v2 + v3 * v3;
#pragma unroll
  for (int mask = 1; mask <= 32; mask <<= 1) {
    s += __shfl_xor(s, mask);
    qq += __shfl_xor(qq, mask);
  }
  float mu = s * (1.f / CH);
  float var = qq * (1.f / CH) - mu * mu;
  float rs = rsqrtf(fmaxf(var, 0.f) + LN_EPS);
  F4 uw = *(const F4*)(w + lane * 4);
  F4 ub = *(const F4*)(b + lane * 4);
  US4 o;
  o.x = f2bf((v0 - mu) * rs * uw.x + ub.x);
  o.y = f2bf((v1 - mu) * rs * uw.y + ub.y);
  o.z = f2bf((v2 - mu) * rs * uw.z + ub.z);
  o.w = f2bf((v3 - mu) * rs * uw.w + ub.w);
  *(US4*)(x4ln + row * CH + lane * 4) = o;
}

// ---------------------------------------------------------------------------
// Final: out[b][c][pos] = x3[b][pos][c] + x4[b][pos][c]  (fp32 out, LDS transpose)
// grid: 1024 (16 b x 16 posblk x 4 cblk), block 256
// ---------------------------------------------------------------------------
__global__ __launch_bounds__(256) void k_add_t(const u16* __restrict__ x3,
                                               const u16* __restrict__ x4,
                                               float* __restrict__ out) {
  __shared__ float tl[64][66];
  const int t = threadIdx.x;
  const int bb = blockIdx.x >> 6;
  const int pb = (blockIdx.x >> 2) & 15, cb = blockIdx.x & 3;
  const int pos0 = pb * 64, c0 = cb * 64;
#pragma unroll
  for (int it = 0; it < 16; ++it) {
    int c_l = t & 63, p_l = it * 4 + (t >> 6);
    size_t ro = ((size_t)bb * NT + pos0 + p_l) * CH + c0 + c_l;
    tl[p_l][c_l] = bf2f(x3[ro]) + bf2f(x4[ro]);
  }
  __syncthreads();
#pragma unroll
  for (int it = 0; it < 16; ++it) {
    int p_l = t & 63, c_l = it * 4 + (t >> 6);
    out[((size_t)bb * CH + c0 + c_l) * NT + pos0 + p_l] = tl[p_l][c_l];
  }
}

// ---------------------------------------------------------------------------
// Launch
// ---------------------------------------------------------------------------
extern "C" void kernel_launch(void* const* d_in, const int* in_sizes, int n_in,
                              void* d_out, int out_size, void* d_ws, size_t ws_size,
                              hipStream_t stream) {
  const float* x       = (const float*)d_in[0];
  const float* qkv_w   = (const float*)d_in[1];
  const float* proj_w  = (const float*)d_in[2];
  const float* proj_b  = (const float*)d_in[3];
  const float* ffn_w1  = (const float*)d_in[4];
  const float* ffn_b1  = (const float*)d_in[5];
  const float* ffn_w2  = (const float*)d_in[6];
  const float* ffn_b2  = (const float*)d_in[7];
  const float* norm1_w = (const float*)d_in[8];
  const float* norm1_b = (const float*)d_in[9];
  const float* norm2_w = (const float*)d_in[10];
  const float* norm2_b = (const float*)d_in[11];
  const float* btab    = (const float*)d_in[12];
  const int* rel       = (const int*)d_in[13];
  float* out = (float*)d_out;

  // Workspace layout (total ~57.5 MB) with lifetime-based aliasing:
  //   region R (33.55 MB): biasT(16.78)+qm(8.39)+km(8.39)  ... reused as ffn_h
  //   vm (8.39)   ... reused as x4ln
  //   bufX (8.39) : x1 -> ao -> x4
  //   x3 (8.39)
  char* ws = (char*)d_ws;
  size_t off = 0;
  auto alloc = [&](size_t bytes) { char* p = ws + off; off += bytes; return p; };
  u16* qkv_wT  = (u16*)alloc((size_t)768 * 256 * 2);
  u16* proj_wT = (u16*)alloc((size_t)256 * 256 * 2);
  u16* w1T     = (u16*)alloc((size_t)1024 * 256 * 2);
  u16* w2T     = (u16*)alloc((size_t)256 * 1024 * 2);
  u16* biasT   = (u16*)alloc((size_t)NH * NT * NT * 2);   // 16.78 MB
  u16* qm      = (u16*)alloc((size_t)MROWS * CH * 2);     // 8.39 MB
  u16* km      = (u16*)alloc((size_t)MROWS * CH * 2);     // 8.39 MB
  u16* vm      = (u16*)alloc((size_t)MROWS * CH * 2);     // 8.39 MB
  u16* bufX    = (u16*)alloc((size_t)MROWS * CH * 2);     // 8.39 MB
  u16* x3      = (u16*)alloc((size_t)MROWS * CH * 2);     // 8.39 MB
  u16* ffn_h = biasT;  // 33.55 MB overlay on biasT+qm+km (dead after attention)
  u16* x4ln  = vm;     // vm dead after attention
  u16* x1 = bufX;      // x1 dead after QKV
  u16* ao = bufX;      // ao dead after proj
  u16* x4 = bufX;      // x4 live until add_t
  (void)ws_size; (void)in_sizes; (void)n_in; (void)out_size;

  // weight transposes (fp32 -> bf16)
  k_transpose<<<dim3(4, 12), 256, 0, stream>>>(qkv_w, qkv_wT, 256, 768);
  k_transpose<<<dim3(4, 4), 256, 0, stream>>>(proj_w, proj_wT, 256, 256);
  k_transpose<<<dim3(4, 16), 256, 0, stream>>>(ffn_w1, w1T, 256, 1024);
  k_transpose<<<dim3(16, 4), 256, 0, stream>>>(ffn_w2, w2T, 1024, 256);
  // bias gather (transposed for b64 loads in attention)
  k_prep_bias<<<256, 256, 0, stream>>>(btab, rel, biasT);
  // LN1 + transpose
  k_ln1<<<BATCH * 16, 256, 0, stream>>>(x, norm1_w, norm1_b, x1);
  // QKV
  k_gemm_qkv<<<dim3(MROWS / 64, 12), 256, 0, stream>>>(x1, qkv_wT, qm, km, vm);
  // attention
  k_attn<<<BATCH * NH * 16, 256, 0, stream>>>(qm, km, vm, biasT, ao);
  // proj + residual
  k_gemm_proj<<<dim3(MROWS / 64, 4), 256, 0, stream>>>(ao, proj_wT, proj_b, x, x3);
  // LN2
  k_ln2<<<MROWS / 4, 256, 0, stream>>>(x3, norm2_w, norm2_b, x4ln);
  // FFN
  k_gemm_ffn1<<<dim3(MROWS / 64, 16), 256, 0, stream>>>(x4ln, w1T, ffn_b1, ffn_h);
  k_gemm_ffn2<<<dim3(MROWS / 64, 4), 256, 0, stream>>>(ffn_h, w2T, ffn_b2, x4);
  // final residual + transpose to (B,C,H,W), fp32 out
  k_add_t<<<BATCH * 16 * 4, 256, 0, stream>>>(x3, x4, out);
}

// Round 4
// 426.035 us; speedup vs baseline: 1.2304x; 1.2304x over previous
//
#include <hip/hip_runtime.h>
#include <math.h>

// ---------------------------------------------------------------------------
// Problem constants
// ---------------------------------------------------------------------------
#define BATCH 16
#define CH    256          // channels C
#define NT    1024         // tokens n = 32*32
#define NH    8            // heads
#define DH    32           // dim_head
#define HID   1024         // ffn hidden
#define MROWS (BATCH * NT) // 16384 rows for all GEMMs
#define LN_EPS 1e-5f

typedef unsigned short u16;
typedef unsigned int u32;
typedef __attribute__((ext_vector_type(8))) short short8;  // 8 x bf16 (4 VGPRs)
typedef __attribute__((ext_vector_type(4))) float f32x4;

struct __align__(8) US4 { u16 x, y, z, w; };
struct __align__(16) F4 { float x, y, z, w; };

#define MFMA(a, b, c) __builtin_amdgcn_mfma_f32_16x16x32_bf16((a), (b), (c), 0, 0, 0)

#define LOG2E 1.4426950408889634f
#define QSCALE (0.17677669529663687f * 1.4426950408889634f)  // scale * log2e

__device__ __forceinline__ float bf2f(u16 u) {
  union { unsigned int i; float f; } v; v.i = ((unsigned int)u) << 16; return v.f;
}
__device__ __forceinline__ u16 f2bf(float f) {
  union { float f; unsigned int i; } v; v.f = f;
  unsigned int i = v.i;
  return (u16)((i + 0x7fffu + ((i >> 16) & 1u)) >> 16);  // RNE
}
// pack trunc-bf16(lo) into low u16, trunc-bf16(hi) into high u16 (1 v_perm)
__device__ __forceinline__ u32 pack_bf16_pair(float lo, float hi) {
  union { float f; u32 i; } a, b; a.f = lo; b.f = hi;
#if __has_builtin(__builtin_amdgcn_perm)
  return __builtin_amdgcn_perm(b.i, a.i, 0x07060302u);
#else
  return (b.i & 0xFFFF0000u) | (a.i >> 16);
#endif
}
__device__ __forceinline__ float fast_exp2(float x) {
#if __has_builtin(__builtin_amdgcn_exp2f)
  return __builtin_amdgcn_exp2f(x);
#else
  return exp2f(x);
#endif
}

// ---------------------------------------------------------------------------
// Weight transpose + fp32->bf16: in (K x N) fp32 -> out (N x K) bf16
// ---------------------------------------------------------------------------
__global__ __launch_bounds__(256) void k_transpose(const float* __restrict__ in,
                                                   u16* __restrict__ out,
                                                   int K, int N) {
  __shared__ u16 tl[64][66];
  const int t = threadIdx.x;
  const int kb = blockIdx.x * 64, nb = blockIdx.y * 64;
#pragma unroll
  for (int it = 0; it < 16; ++it) {
    int n_l = t & 63, k_l = it * 4 + (t >> 6);
    tl[k_l][n_l] = f2bf(in[(size_t)(kb + k_l) * N + nb + n_l]);
  }
  __syncthreads();
#pragma unroll
  for (int it = 0; it < 16; ++it) {
    int k_l = t & 63, n_l = it * 4 + (t >> 6);
    out[(size_t)(nb + n_l) * K + kb + k_l] = tl[k_l][n_l];
  }
}

// ---------------------------------------------------------------------------
// Bias pre-gather, scaled by log2e, paired layout for 1-b128 tile loads:
//   biasB element offset = h*1048576 + (j>>1)*2048 + i*2 + (j&1)
//   i.e. dword[h][jp][i] = { bf16(bias(2jp, i)*log2e), bf16(bias(2jp+1, i)*log2e) }
// grid: 256 (16 jb x 16 ib), block 256
// ---------------------------------------------------------------------------
__global__ __launch_bounds__(256) void k_prep_bias(const float* __restrict__ table,
                                                   const int* __restrict__ rel,
                                                   u16* __restrict__ biasB) {
  __shared__ u16 tl[64][66];  // [j_local][i_local]
  const int t = threadIdx.x;
  const int jb = (blockIdx.x & 15) * 64, ib = (blockIdx.x >> 4) * 64;
  int idxs[16];
#pragma unroll
  for (int it = 0; it < 16; ++it) {
    int j_l = t & 63, i_l = it * 4 + (t >> 6);
    idxs[it] = rel[(size_t)(ib + i_l) * NT + jb + j_l];
  }
  u32* outd = (u32*)biasB;
  for (int h = 0; h < NH; ++h) {
    __syncthreads();
#pragma unroll
    for (int it = 0; it < 16; ++it) {
      int j_l = t & 63, i_l = it * 4 + (t >> 6);
      tl[j_l][i_l] = f2bf(table[(size_t)idxs[it] * NH + h] * LOG2E);
    }
    __syncthreads();
#pragma unroll
    for (int it = 0; it < 8; ++it) {
      int i_l = t & 63, jp_l = it * 4 + (t >> 6);  // 32 j-pairs per 64-j tile
      u32 v = (u32)tl[2 * jp_l][i_l] | ((u32)tl[2 * jp_l + 1][i_l] << 16);
      outd[(size_t)h * 524288 + (size_t)((jb >> 1) + jp_l) * 1024 + ib + i_l] = v;
    }
  }
}

// ---------------------------------------------------------------------------
// LN1 fused with (B,C,n) -> (B,n,C) transpose + fp32->bf16.
// ---------------------------------------------------------------------------
__global__ __launch_bounds__(256) void k_ln1(const float* __restrict__ x,
                                             const float* __restrict__ w,
                                             const float* __restrict__ b,
                                             u16* __restrict__ x1) {
  __shared__ u16 tile[CH][68];
  __shared__ float red_s[4][64], red_q[4][64], mu_s[64], rs_s[64];
  const int t = threadIdx.x;
  const int bb = blockIdx.x >> 4, pb = blockIdx.x & 15;
  const int pos0 = pb * 64;
#pragma unroll
  for (int it = 0; it < 16; ++it) {
    int c = it * 16 + (t >> 4), p4 = (t & 15) * 4;
    F4 v = *(const F4*)(x + ((size_t)bb * CH + c) * NT + pos0 + p4);
    US4 o; o.x = f2bf(v.x); o.y = f2bf(v.y); o.z = f2bf(v.z); o.w = f2bf(v.w);
    *(US4*)&tile[c][p4] = o;
  }
  __syncthreads();
  {
    int pos = t & 63, g = t >> 6;
    float s = 0.f, q = 0.f;
#pragma unroll 8
    for (int cc = 0; cc < 64; ++cc) {
      float v = bf2f(tile[g * 64 + cc][pos]);
      s += v; q += v * v;
    }
    red_s[g][pos] = s; red_q[g][pos] = q;
  }
  __syncthreads();
  if (t < 64) {
    float s = red_s[0][t] + red_s[1][t] + red_s[2][t] + red_s[3][t];
    float q = red_q[0][t] + red_q[1][t] + red_q[2][t] + red_q[3][t];
    float mu = s * (1.f / CH);
    float var = q * (1.f / CH) - mu * mu;
    mu_s[t] = mu;
    rs_s[t] = rsqrtf(fmaxf(var, 0.f) + LN_EPS);
  }
  __syncthreads();
  {
    const int c = t;
    const float wv = w[c], bv = b[c];
    for (int pos = 0; pos < 64; ++pos) {
      float v = (bf2f(tile[c][pos]) - mu_s[pos]) * rs_s[pos] * wv + bv;
      x1[((size_t)bb * NT + pos0 + pos) * CH + c] = f2bf(v);
    }
  }
}

// ---------------------------------------------------------------------------
// MFMA GEMM core: C[64x64 per block] = A(MxK) @ Bt(NxK)^T, 4 waves x (16x64)
// ---------------------------------------------------------------------------
template <int K>
__device__ __forceinline__ void gemm_core(const u16* __restrict__ A,
                                          const u16* __restrict__ Bt,
                                          int r0, int c0, f32x4 acc[4]) {
  const int lane = threadIdx.x & 63;
  const int l16 = lane & 15, quad = lane >> 4;
  const u16* ap = A + (size_t)(r0 + l16) * K + quad * 8;
  const u16* bp = Bt + (size_t)(c0 + l16) * K + quad * 8;
#pragma unroll 8
  for (int k0 = 0; k0 < K; k0 += 32) {
    short8 a = *(const short8*)(ap + k0);
#pragma unroll
    for (int j = 0; j < 4; ++j) {
      short8 bfr = *(const short8*)(bp + (size_t)j * 16 * K + k0);
      acc[j] = MFMA(a, bfr, acc[j]);
    }
  }
}

// QKV: x1(16384x256) @ qkv_wT -> q (pre-scaled by scale*log2e, B,H,n,d),
//      k (B,H,n,d), v TRANSPOSED (B,H,d,n)
__global__ __launch_bounds__(256) void k_gemm_qkv(const u16* __restrict__ x1,
                                                  const u16* __restrict__ wT,
                                                  u16* __restrict__ q,
                                                  u16* __restrict__ k,
                                                  u16* __restrict__ vT) {
  const int wave = threadIdx.x >> 6, lane = threadIdx.x & 63;
  const int l16 = lane & 15, quad = lane >> 4;
  const int r0 = blockIdx.x * 64 + wave * 16, c0 = blockIdx.y * 64;
  f32x4 acc[4];
#pragma unroll
  for (int j = 0; j < 4; ++j) acc[j] = 0.f;
  gemm_core<CH>(x1, wT, r0, c0, acc);
#pragma unroll
  for (int j = 0; j < 4; ++j) {
    int col = c0 + j * 16 + l16;
    int which = col >> 8, rem = col & 255, h = rem >> 5, dd = rem & 31;
    if (which == 2) {
      // V: write transposed (B,H,DH,NT); 4 consecutive pos -> one US4
      int row0 = r0 + quad * 4;
      int bb = row0 >> 10, pos = row0 & 1023;
      US4 o;
      o.x = f2bf(acc[j][0]); o.y = f2bf(acc[j][1]);
      o.z = f2bf(acc[j][2]); o.w = f2bf(acc[j][3]);
      *(US4*)(vT + (((size_t)bb * NH + h) * DH + dd) * NT + pos) = o;
    } else {
      u16* dst = (which == 0) ? q : k;
      float mul = (which == 0) ? QSCALE : 1.0f;
#pragma unroll
      for (int r = 0; r < 4; ++r) {
        int row = r0 + quad * 4 + r;
        int bb = row >> 10, pos = row & 1023;
        dst[(((size_t)bb * NH + h) * NT + pos) * DH + dd] = f2bf(acc[j][r] * mul);
      }
    }
  }
}

// PROJ: attn_out(16384x256) @ proj_wT + proj_b + x^T -> x3 (B,n,C) bf16
__global__ __launch_bounds__(256) void k_gemm_proj(const u16* __restrict__ ao,
                                                   const u16* __restrict__ wT,
                                                   const float* __restrict__ pb,
                                                   const float* __restrict__ x,
                                                   u16* __restrict__ x3) {
  const int wave = threadIdx.x >> 6, lane = threadIdx.x & 63;
  const int l16 = lane & 15, quad = lane >> 4;
  const int r0 = blockIdx.x * 64 + wave * 16, c0 = blockIdx.y * 64;
  f32x4 acc[4];
#pragma unroll
  for (int j = 0; j < 4; ++j) acc[j] = 0.f;
  gemm_core<CH>(ao, wT, r0, c0, acc);
#pragma unroll
  for (int j = 0; j < 4; ++j) {
    int col = c0 + j * 16 + l16;
    float bias = pb[col];
#pragma unroll
    for (int r = 0; r < 4; ++r) {
      int row = r0 + quad * 4 + r;
      int bb = row >> 10, pos = row & 1023;
      float val = acc[j][r] + bias + x[((size_t)bb * CH + col) * NT + pos];
      x3[(size_t)row * CH + col] = f2bf(val);
    }
  }
}

// FFN1: x4ln(16384x256) @ w1T + b1, exact GELU -> ffn_h (16384x1024) bf16
__global__ __launch_bounds__(256) void k_gemm_ffn1(const u16* __restrict__ a,
                                                   const u16* __restrict__ wT,
                                                   const float* __restrict__ b1,
                                                   u16* __restrict__ hmat) {
  const int wave = threadIdx.x >> 6, lane = threadIdx.x & 63;
  const int l16 = lane & 15, quad = lane >> 4;
  const int r0 = blockIdx.x * 64 + wave * 16, c0 = blockIdx.y * 64;
  f32x4 acc[4];
#pragma unroll
  for (int j = 0; j < 4; ++j) acc[j] = 0.f;
  gemm_core<CH>(a, wT, r0, c0, acc);
#pragma unroll
  for (int j = 0; j < 4; ++j) {
    int col = c0 + j * 16 + l16;
    float bias = b1[col];
#pragma unroll
    for (int r = 0; r < 4; ++r) {
      int row = r0 + quad * 4 + r;
      float v = acc[j][r] + bias;
      float g = 0.5f * v * (1.0f + erff(v * 0.70710678118654752f));
      hmat[(size_t)row * HID + col] = f2bf(g);
    }
  }
}

// FFN2: ffn_h(16384x1024) @ w2T + b2 -> x4 (B,n,C) bf16
__global__ __launch_bounds__(256) void k_gemm_ffn2(const u16* __restrict__ a,
                                                   const u16* __restrict__ wT,
                                                   const float* __restrict__ b2,
                                                   u16* __restrict__ x4) {
  const int wave = threadIdx.x >> 6, lane = threadIdx.x & 63;
  const int l16 = lane & 15, quad = lane >> 4;
  const int r0 = blockIdx.x * 64 + wave * 16, c0 = blockIdx.y * 64;
  f32x4 acc[4];
#pragma unroll
  for (int j = 0; j < 4; ++j) acc[j] = 0.f;
  gemm_core<HID>(a, wT, r0, c0, acc);
#pragma unroll
  for (int j = 0; j < 4; ++j) {
    int col = c0 + j * 16 + l16;
    float bias = b2[col];
#pragma unroll
    for (int r = 0; r < 4; ++r) {
      int row = r0 + quad * 4 + r;
      x4[(size_t)row * CH + col] = f2bf(acc[j][r] + bias);
    }
  }
}

// ---------------------------------------------------------------------------
// Flash attention, fixed-max softmax (scores bounded; exp2 safe in fp32):
//  - q pre-scaled by scale*log2e, bias pre-scaled by log2e (in C-operand)
//  - Ks rows permuted: even keys -> rows 0-15, odd -> rows 16-31 of each
//    32-block, so (s0[r], s1[r]) are adjacent keys -> 1 v_perm pack -> b32 P
//  - V staged from pre-transposed vT (vectorized, conflict-free)
//  - l = per-lane partial sums, one butterfly at the end
// grid: 2048, block 256
// ---------------------------------------------------------------------------
__global__ __launch_bounds__(256) void k_attn(const u16* __restrict__ q,
                                              const u16* __restrict__ k,
                                              const u16* __restrict__ vT,
                                              const u16* __restrict__ biasB,
                                              u16* __restrict__ ao) {
  __shared__ u16 Ks[256][40];   // permuted rows; stride 80 B (16B multiple)
  __shared__ u16 Vt[32][264];   // [d][j], stride 528 B (16B multiple)
  __shared__ u16 Ps[4][16][40]; // per-wave P staging (written as b32)
  const int tid = threadIdx.x;
  const int wave = tid >> 6, lane = tid & 63;
  const int quad = lane >> 4, l16 = lane & 15;
  const int bh = blockIdx.x >> 4, qt = blockIdx.x & 15;
  const int h = bh & 7, bb = bh >> 3;
  const int i0 = qt * 64 + wave * 16;

  short8 aq = *(const short8*)(q + ((size_t)bh * NT + i0 + l16) * DH + quad * 8);
  const u16* bias_h = biasB + (size_t)h * 1048576 + (size_t)(i0 + quad * 4) * 2;

  float l_loc[4] = {0.f, 0.f, 0.f, 0.f};
  f32x4 acc0 = 0.f, acc1 = 0.f;

  for (int chunk = 0; chunk < 4; ++chunk) {
    __syncthreads();
    const int rbase = chunk * 256;
    {
      // K: permuted-row staging (US4 per thread)
      const int srow = tid >> 3, sdd = (tid & 7) * 4;
#pragma unroll
      for (int it = 0; it < 8; ++it) {
        int rl = it * 32 + srow;
        int rowL = (rl & ~31) | ((rl & 31) >> 1) | ((rl & 1) << 4);
        US4 kv = *(const US4*)(k + ((size_t)bh * NT + rbase + rl) * DH + sdd);
        *(US4*)&Ks[rowL][sdd] = kv;
      }
      // V: row copies from vT (d-major), vectorized
      const int j4 = (tid & 63) * 4;
#pragma unroll
      for (int it = 0; it < 8; ++it) {
        int d = it * 4 + wave;
        US4 vv = *(const US4*)(vT + ((size_t)bh * DH + d) * NT + rbase + j4);
        *(US4*)&Vt[d][j4] = vv;
      }
    }
    __syncthreads();

#pragma unroll 2
    for (int j0 = 0; j0 < 256; j0 += 32) {
      short8 bk0 = *(const short8*)&Ks[j0 + l16][quad * 8];       // even keys
      short8 bk1 = *(const short8*)&Ks[j0 + 16 + l16][quad * 8];  // odd keys
      // bias tile: one b128 = 8 u16 {(r, par)} at j-pair (rbase+j0)/2 + l16
      short8 be = *(const short8*)(bias_h +
                   ((size_t)((rbase + j0) >> 1) + l16) * 2048);
      const u16* bep = (const u16*)&be;
      f32x4 c0, c1;
#pragma unroll
      for (int r = 0; r < 4; ++r) {
        c0[r] = bf2f(bep[2 * r]);
        c1[r] = bf2f(bep[2 * r + 1]);
      }
      f32x4 s0 = MFMA(aq, bk0, c0);  // score*scale*log2e + bias*log2e
      f32x4 s1 = MFMA(aq, bk1, c1);
      u32 packed[4];
#pragma unroll
      for (int r = 0; r < 4; ++r) {
        float p0 = fast_exp2(s0[r]);
        float p1 = fast_exp2(s1[r]);
        l_loc[r] += p0 + p1;
        packed[r] = pack_bf16_pair(p0, p1);  // keys (2l16, 2l16+1)
      }
      u32* psw = (u32*)&Ps[wave][0][0];
#pragma unroll
      for (int r = 0; r < 4; ++r) psw[(quad * 4 + r) * 20 + l16] = packed[r];
      // wave-synchronous LDS round-trip (C/D layout -> A layout, natural key order)
      short8 ap  = *(const short8*)&Ps[wave][l16][quad * 8];
      short8 bv0 = *(const short8*)&Vt[l16][j0 + quad * 8];
      short8 bv1 = *(const short8*)&Vt[16 + l16][j0 + quad * 8];
      acc0 = MFMA(ap, bv0, acc0);
      acc1 = MFMA(ap, bv1, acc1);
    }
  }
  // one final reduction of l over the 16 key-lanes
#pragma unroll
  for (int mask = 1; mask <= 8; mask <<= 1) {
#pragma unroll
    for (int r = 0; r < 4; ++r) l_loc[r] += __shfl_xor(l_loc[r], mask);
  }
#pragma unroll
  for (int r = 0; r < 4; ++r) {
    float inv = 1.0f / l_loc[r];
    int row = i0 + quad * 4 + r;
    u16* o = ao + ((size_t)bb * NT + row) * CH + h * DH;
    o[l16]      = f2bf(acc0[r] * inv);
    o[16 + l16] = f2bf(acc1[r] * inv);
  }
}

// ---------------------------------------------------------------------------
// LN2: x3 (B,n,C) bf16 rows contiguous -> x4ln (B,n,C) bf16. One wave per row.
// ---------------------------------------------------------------------------
__global__ __launch_bounds__(256) void k_ln2(const u16* __restrict__ x3,
                                             const float* __restrict__ w,
                                             const float* __restrict__ b,
                                             u16* __restrict__ x4ln) {
  const int wave = threadIdx.x >> 6, lane = threadIdx.x & 63;
  const size_t row = (size_t)blockIdx.x * 4 + wave;
  US4 u = *(const US4*)(x3 + row * CH + lane * 4);
  float v0 = bf2f(u.x), v1 = bf2f(u.y), v2 = bf2f(u.z), v3 = bf2f(u.w);
  float s = v0 + v1 + v2 + v3;
  float qq = v0 * v0 + v1 * v1 + v2 * v2 + v3 * v3;
#pragma unroll
  for (int mask = 1; mask <= 32; mask <<= 1) {
    s += __shfl_xor(s, mask);
    qq += __shfl_xor(qq, mask);
  }
  float mu = s * (1.f / CH);
  float var = qq * (1.f / CH) - mu * mu;
  float rs = rsqrtf(fmaxf(var, 0.f) + LN_EPS);
  F4 uw = *(const F4*)(w + lane * 4);
  F4 ub = *(const F4*)(b + lane * 4);
  US4 o;
  o.x = f2bf((v0 - mu) * rs * uw.x + ub.x);
  o.y = f2bf((v1 - mu) * rs * uw.y + ub.y);
  o.z = f2bf((v2 - mu) * rs * uw.z + ub.z);
  o.w = f2bf((v3 - mu) * rs * uw.w + ub.w);
  *(US4*)(x4ln + row * CH + lane * 4) = o;
}

// ---------------------------------------------------------------------------
// Final: out[b][c][pos] = x3[b][pos][c] + x4[b][pos][c]  (fp32 out)
// ---------------------------------------------------------------------------
__global__ __launch_bounds__(256) void k_add_t(const u16* __restrict__ x3,
                                               const u16* __restrict__ x4,
                                               float* __restrict__ out) {
  __shared__ float tl[64][66];
  const int t = threadIdx.x;
  const int bb = blockIdx.x >> 6;
  const int pb = (blockIdx.x >> 2) & 15, cb = blockIdx.x & 3;
  const int pos0 = pb * 64, c0 = cb * 64;
#pragma unroll
  for (int it = 0; it < 16; ++it) {
    int c_l = t & 63, p_l = it * 4 + (t >> 6);
    size_t ro = ((size_t)bb * NT + pos0 + p_l) * CH + c0 + c_l;
    tl[p_l][c_l] = bf2f(x3[ro]) + bf2f(x4[ro]);
  }
  __syncthreads();
#pragma unroll
  for (int it = 0; it < 16; ++it) {
    int p_l = t & 63, c_l = it * 4 + (t >> 6);
    out[((size_t)bb * CH + c0 + c_l) * NT + pos0 + p_l] = tl[p_l][c_l];
  }
}

// ---------------------------------------------------------------------------
// Launch
// ---------------------------------------------------------------------------
extern "C" void kernel_launch(void* const* d_in, const int* in_sizes, int n_in,
                              void* d_out, int out_size, void* d_ws, size_t ws_size,
                              hipStream_t stream) {
  const float* x       = (const float*)d_in[0];
  const float* qkv_w   = (const float*)d_in[1];
  const float* proj_w  = (const float*)d_in[2];
  const float* proj_b  = (const float*)d_in[3];
  const float* ffn_w1  = (const float*)d_in[4];
  const float* ffn_b1  = (const float*)d_in[5];
  const float* ffn_w2  = (const float*)d_in[6];
  const float* ffn_b2  = (const float*)d_in[7];
  const float* norm1_w = (const float*)d_in[8];
  const float* norm1_b = (const float*)d_in[9];
  const float* norm2_w = (const float*)d_in[10];
  const float* norm2_b = (const float*)d_in[11];
  const float* btab    = (const float*)d_in[12];
  const int* rel       = (const int*)d_in[13];
  float* out = (float*)d_out;

  char* ws = (char*)d_ws;
  size_t off = 0;
  auto alloc = [&](size_t bytes) { char* p = ws + off; off += bytes; return p; };
  u16* qkv_wT  = (u16*)alloc((size_t)768 * 256 * 2);
  u16* proj_wT = (u16*)alloc((size_t)256 * 256 * 2);
  u16* w1T     = (u16*)alloc((size_t)1024 * 256 * 2);
  u16* w2T     = (u16*)alloc((size_t)256 * 1024 * 2);
  u16* biasB   = (u16*)alloc((size_t)NH * NT * NT * 2);   // 16.78 MB
  u16* qm      = (u16*)alloc((size_t)MROWS * CH * 2);     // 8.39 MB
  u16* km      = (u16*)alloc((size_t)MROWS * CH * 2);     // 8.39 MB
  u16* vm      = (u16*)alloc((size_t)MROWS * CH * 2);     // 8.39 MB (as vT)
  u16* bufX    = (u16*)alloc((size_t)MROWS * CH * 2);     // 8.39 MB
  u16* x3      = (u16*)alloc((size_t)MROWS * CH * 2);     // 8.39 MB
  u16* ffn_h = biasB;  // overlay (dead after attention)
  u16* x4ln  = vm;     // overlay (dead after attention)
  u16* x1 = bufX;
  u16* ao = bufX;
  u16* x4 = bufX;
  (void)ws_size; (void)in_sizes; (void)n_in; (void)out_size;

  k_transpose<<<dim3(4, 12), 256, 0, stream>>>(qkv_w, qkv_wT, 256, 768);
  k_transpose<<<dim3(4, 4), 256, 0, stream>>>(proj_w, proj_wT, 256, 256);
  k_transpose<<<dim3(4, 16), 256, 0, stream>>>(ffn_w1, w1T, 256, 1024);
  k_transpose<<<dim3(16, 4), 256, 0, stream>>>(ffn_w2, w2T, 1024, 256);
  k_prep_bias<<<256, 256, 0, stream>>>(btab, rel, biasB);
  k_ln1<<<BATCH * 16, 256, 0, stream>>>(x, norm1_w, norm1_b, x1);
  k_gemm_qkv<<<dim3(MROWS / 64, 12), 256, 0, stream>>>(x1, qkv_wT, qm, km, vm);
  k_attn<<<BATCH * NH * 16, 256, 0, stream>>>(qm, km, vm, biasB, ao);
  k_gemm_proj<<<dim3(MROWS / 64, 4), 256, 0, stream>>>(ao, proj_wT, proj_b, x, x3);
  k_ln2<<<MROWS / 4, 256, 0, stream>>>(x3, norm2_w, norm2_b, x4ln);
  k_gemm_ffn1<<<dim3(MROWS / 64, 16), 256, 0, stream>>>(x4ln, w1T, ffn_b1, ffn_h);
  k_gemm_ffn2<<<dim3(MROWS / 64, 4), 256, 0, stream>>>(ffn_h, w2T, ffn_b2, x4);
  k_add_t<<<BATCH * 16 * 4, 256, 0, stream>>>(x3, x4, out);
}

// Round 5
// 271.888 us; speedup vs baseline: 1.9279x; 1.5669x over previous
//
#include <hip/hip_runtime.h>
#include <math.h>

// ---------------------------------------------------------------------------
// Problem constants
// ---------------------------------------------------------------------------
#define BATCH 16
#define CH    256          // channels C
#define NT    1024         // tokens n = 32*32
#define NH    8            // heads
#define DH    32           // dim_head
#define HID   1024         // ffn hidden
#define MROWS (BATCH * NT) // 16384 rows for all GEMMs
#define LN_EPS 1e-5f

typedef unsigned short u16;
typedef unsigned int u32;
typedef __attribute__((ext_vector_type(8))) short short8;  // 8 x bf16 (4 VGPRs)
typedef __attribute__((ext_vector_type(4))) float f32x4;

struct __align__(8) US4 { u16 x, y, z, w; };
struct __align__(16) F4 { float x, y, z, w; };

#define MFMA(a, b, c) __builtin_amdgcn_mfma_f32_16x16x32_bf16((a), (b), (c), 0, 0, 0)

#define LOG2E 1.4426950408889634f
#define QSCALE (0.17677669529663687f * 1.4426950408889634f)  // scale * log2e

__device__ __forceinline__ float bf2f(u16 u) {
  union { unsigned int i; float f; } v; v.i = ((unsigned int)u) << 16; return v.f;
}
__device__ __forceinline__ u16 f2bf(float f) {
  union { float f; unsigned int i; } v; v.f = f;
  unsigned int i = v.i;
  return (u16)((i + 0x7fffu + ((i >> 16) & 1u)) >> 16);  // RNE
}
__device__ __forceinline__ u32 pack_bf16_pair(float lo, float hi) {
  union { float f; u32 i; } a, b; a.f = lo; b.f = hi;
#if __has_builtin(__builtin_amdgcn_perm)
  return __builtin_amdgcn_perm(b.i, a.i, 0x07060302u);
#else
  return (b.i & 0xFFFF0000u) | (a.i >> 16);
#endif
}
__device__ __forceinline__ float fast_exp2(float x) {
#if __has_builtin(__builtin_amdgcn_exp2f)
  return __builtin_amdgcn_exp2f(x);
#else
  return exp2f(x);
#endif
}
// async global->LDS, 16 B per lane; LDS dest = uniform base + lane*16
__device__ __forceinline__ void llds16(const u16* g, u16* l) {
  __builtin_amdgcn_global_load_lds(
      (const __attribute__((address_space(1))) u32*)g,
      (__attribute__((address_space(3))) u32*)l, 16, 0, 0);
}

// ---------------------------------------------------------------------------
// Weight transpose + fp32->bf16: in (K x N) fp32 -> out (N x K) bf16
// ---------------------------------------------------------------------------
__global__ __launch_bounds__(256) void k_transpose(const float* __restrict__ in,
                                                   u16* __restrict__ out,
                                                   int K, int N) {
  __shared__ u16 tl[64][66];
  const int t = threadIdx.x;
  const int kb = blockIdx.x * 64, nb = blockIdx.y * 64;
#pragma unroll
  for (int it = 0; it < 16; ++it) {
    int n_l = t & 63, k_l = it * 4 + (t >> 6);
    tl[k_l][n_l] = f2bf(in[(size_t)(kb + k_l) * N + nb + n_l]);
  }
  __syncthreads();
#pragma unroll
  for (int it = 0; it < 16; ++it) {
    int k_l = t & 63, n_l = it * 4 + (t >> 6);
    out[(size_t)(nb + n_l) * K + kb + k_l] = tl[k_l][n_l];
  }
}

// ---------------------------------------------------------------------------
// Bias pre-gather, scaled by log2e, paired layout for 1-b128 tile loads:
//   dword[h][jp][i] = { bf16(bias(2jp, i)*log2e), bf16(bias(2jp+1, i)*log2e) }
// ---------------------------------------------------------------------------
__global__ __launch_bounds__(256) void k_prep_bias(const float* __restrict__ table,
                                                   const int* __restrict__ rel,
                                                   u16* __restrict__ biasB) {
  __shared__ u16 tl[64][66];  // [j_local][i_local]
  const int t = threadIdx.x;
  const int jb = (blockIdx.x & 15) * 64, ib = (blockIdx.x >> 4) * 64;
  int idxs[16];
#pragma unroll
  for (int it = 0; it < 16; ++it) {
    int j_l = t & 63, i_l = it * 4 + (t >> 6);
    idxs[it] = rel[(size_t)(ib + i_l) * NT + jb + j_l];
  }
  u32* outd = (u32*)biasB;
  for (int h = 0; h < NH; ++h) {
    __syncthreads();
#pragma unroll
    for (int it = 0; it < 16; ++it) {
      int j_l = t & 63, i_l = it * 4 + (t >> 6);
      tl[j_l][i_l] = f2bf(table[(size_t)idxs[it] * NH + h] * LOG2E);
    }
    __syncthreads();
#pragma unroll
    for (int it = 0; it < 8; ++it) {
      int i_l = t & 63, jp_l = it * 4 + (t >> 6);
      u32 v = (u32)tl[2 * jp_l][i_l] | ((u32)tl[2 * jp_l + 1][i_l] << 16);
      outd[(size_t)h * 524288 + (size_t)((jb >> 1) + jp_l) * 1024 + ib + i_l] = v;
    }
  }
}

// ---------------------------------------------------------------------------
// LN1 fused with (B,C,n) -> (B,n,C) transpose + fp32->bf16.
// ---------------------------------------------------------------------------
__global__ __launch_bounds__(256) void k_ln1(const float* __restrict__ x,
                                             const float* __restrict__ w,
                                             const float* __restrict__ b,
                                             u16* __restrict__ x1) {
  __shared__ u16 tile[CH][68];
  __shared__ float red_s[4][64], red_q[4][64], mu_s[64], rs_s[64];
  const int t = threadIdx.x;
  const int bb = blockIdx.x >> 4, pb = blockIdx.x & 15;
  const int pos0 = pb * 64;
#pragma unroll
  for (int it = 0; it < 16; ++it) {
    int c = it * 16 + (t >> 4), p4 = (t & 15) * 4;
    F4 v = *(const F4*)(x + ((size_t)bb * CH + c) * NT + pos0 + p4);
    US4 o; o.x = f2bf(v.x); o.y = f2bf(v.y); o.z = f2bf(v.z); o.w = f2bf(v.w);
    *(US4*)&tile[c][p4] = o;
  }
  __syncthreads();
  {
    int pos = t & 63, g = t >> 6;
    float s = 0.f, q = 0.f;
#pragma unroll 8
    for (int cc = 0; cc < 64; ++cc) {
      float v = bf2f(tile[g * 64 + cc][pos]);
      s += v; q += v * v;
    }
    red_s[g][pos] = s; red_q[g][pos] = q;
  }
  __syncthreads();
  if (t < 64) {
    float s = red_s[0][t] + red_s[1][t] + red_s[2][t] + red_s[3][t];
    float q = red_q[0][t] + red_q[1][t] + red_q[2][t] + red_q[3][t];
    float mu = s * (1.f / CH);
    float var = q * (1.f / CH) - mu * mu;
    mu_s[t] = mu;
    rs_s[t] = rsqrtf(fmaxf(var, 0.f) + LN_EPS);
  }
  __syncthreads();
  {
    const int c = t;
    const float wv = w[c], bv = b[c];
    for (int pos = 0; pos < 64; ++pos) {
      float v = (bf2f(tile[c][pos]) - mu_s[pos]) * rs_s[pos] * wv + bv;
      x1[((size_t)bb * NT + pos0 + pos) * CH + c] = f2bf(v);
    }
  }
}

// ---------------------------------------------------------------------------
// m97-style LDS-staged GEMM core: 128x128 block tile, BK=32, 4 waves x 64x64.
// A (MxK row-major), Bt (NxK row-major). acc[i][j]: i = row tile, j = col tile.
// LDS tiles [128][32] contiguous (exact lane order for global_load_lds w=16).
// ---------------------------------------------------------------------------
template <int K>
__device__ __forceinline__ void gemm128(const u16* __restrict__ A,
                                        const u16* __restrict__ Bt,
                                        int r0, int c0, int tid,
                                        u16* lA, u16* lB,
                                        f32x4 acc[4][4]) {
  const int wave = tid >> 6, lane = tid & 63;
  const int wm = (wave >> 1) * 64, wn = (wave & 1) * 64;
  const int l16 = lane & 15, quad = lane >> 4;
  // staging: wave w covers rows [w*16, w*16+16) and [w*16+64, w*16+80)
  const int srow = lane >> 2;        // 0..15 within the 16-row slab
  const int scol = (lane & 3) * 8;   // 0,8,16,24
  const u16* gA0 = A + (size_t)(r0 + wave * 16 + srow) * K + scol;
  const u16* gA1 = A + (size_t)(r0 + wave * 16 + 64 + srow) * K + scol;
  const u16* gB0 = Bt + (size_t)(c0 + wave * 16 + srow) * K + scol;
  const u16* gB1 = Bt + (size_t)(c0 + wave * 16 + 64 + srow) * K + scol;
  u16* lA0 = lA + (wave * 16) * 32;        // wave-uniform LDS bases
  u16* lA1 = lA + (wave * 16 + 64) * 32;
  u16* lB0 = lB + (wave * 16) * 32;
  u16* lB1 = lB + (wave * 16 + 64) * 32;
  for (int k0 = 0; k0 < K; k0 += 32) {
    __syncthreads();
    llds16(gA0 + k0, lA0);
    llds16(gA1 + k0, lA1);
    llds16(gB0 + k0, lB0);
    llds16(gB1 + k0, lB1);
    __syncthreads();
    short8 af[4], bf[4];
#pragma unroll
    for (int i = 0; i < 4; ++i)
      af[i] = *(const short8*)&lA[(wm + i * 16 + l16) * 32 + quad * 8];
#pragma unroll
    for (int j = 0; j < 4; ++j)
      bf[j] = *(const short8*)&lB[(wn + j * 16 + l16) * 32 + quad * 8];
#pragma unroll
    for (int i = 0; i < 4; ++i)
#pragma unroll
      for (int j = 0; j < 4; ++j)
        acc[i][j] = MFMA(af[i], bf[j], acc[i][j]);
  }
}

#define GEMM_PROLOGUE(KVAL, APTR, BPTR)                                  \
  __shared__ __align__(16) u16 lA[128 * 32];                             \
  __shared__ __align__(16) u16 lB[128 * 32];                             \
  const int tid = threadIdx.x;                                           \
  const int wave = tid >> 6, lane = tid & 63;                            \
  const int wm = (wave >> 1) * 64, wn = (wave & 1) * 64;                 \
  const int l16 = lane & 15, quad = lane >> 4;                           \
  const int r0 = blockIdx.x * 128, c0 = blockIdx.y * 128;                \
  f32x4 acc[4][4];                                                       \
  _Pragma("unroll") for (int i = 0; i < 4; ++i)                          \
  _Pragma("unroll") for (int j = 0; j < 4; ++j) acc[i][j] = 0.f;         \
  gemm128<KVAL>(APTR, BPTR, r0, c0, tid, lA, lB, acc);

// QKV: x1(16384x256) @ qkv_wT(768x256)^T -> q (scaled), k, vT (B,H,d,n)
__global__ __launch_bounds__(256) void k_gemm_qkv(const u16* __restrict__ x1,
                                                  const u16* __restrict__ wT,
                                                  u16* __restrict__ q,
                                                  u16* __restrict__ k,
                                                  u16* __restrict__ vT) {
  GEMM_PROLOGUE(CH, x1, wT)
#pragma unroll
  for (int j = 0; j < 4; ++j) {
    int col = c0 + wn + j * 16 + l16;
    int which = col >> 8, rem = col & 255, h = rem >> 5, dd = rem & 31;
#pragma unroll
    for (int i = 0; i < 4; ++i) {
      int row0 = r0 + wm + i * 16 + quad * 4;
      int bb = row0 >> 10, pos = row0 & 1023;
      if (which == 2) {
        US4 o;
        o.x = f2bf(acc[i][j][0]); o.y = f2bf(acc[i][j][1]);
        o.z = f2bf(acc[i][j][2]); o.w = f2bf(acc[i][j][3]);
        *(US4*)(vT + (((size_t)bb * NH + h) * DH + dd) * NT + pos) = o;
      } else {
        u16* dst = (which == 0) ? q : k;
        float mul = (which == 0) ? QSCALE : 1.0f;
#pragma unroll
        for (int r = 0; r < 4; ++r)
          dst[(((size_t)bb * NH + h) * NT + pos + r) * DH + dd] =
              f2bf(acc[i][j][r] * mul);
      }
    }
  }
}

// PROJ: attn_out(16384x256) @ proj_wT + proj_b + x^T -> x3 (B,n,C) bf16
__global__ __launch_bounds__(256) void k_gemm_proj(const u16* __restrict__ ao,
                                                   const u16* __restrict__ wT,
                                                   const float* __restrict__ pb,
                                                   const float* __restrict__ x,
                                                   u16* __restrict__ x3) {
  GEMM_PROLOGUE(CH, ao, wT)
#pragma unroll
  for (int j = 0; j < 4; ++j) {
    int col = c0 + wn + j * 16 + l16;
    float bias = pb[col];
#pragma unroll
    for (int i = 0; i < 4; ++i) {
      int row0 = r0 + wm + i * 16 + quad * 4;
      int bb = row0 >> 10, pos = row0 & 1023;
#pragma unroll
      for (int r = 0; r < 4; ++r) {
        float val = acc[i][j][r] + bias + x[((size_t)bb * CH + col) * NT + pos + r];
        x3[(size_t)(row0 + r) * CH + col] = f2bf(val);
      }
    }
  }
}

// FFN1: x4ln(16384x256) @ w1T + b1, exact GELU -> ffn_h (16384x1024) bf16
__global__ __launch_bounds__(256) void k_gemm_ffn1(const u16* __restrict__ a,
                                                   const u16* __restrict__ wT,
                                                   const float* __restrict__ b1,
                                                   u16* __restrict__ hmat) {
  GEMM_PROLOGUE(CH, a, wT)
#pragma unroll
  for (int j = 0; j < 4; ++j) {
    int col = c0 + wn + j * 16 + l16;
    float bias = b1[col];
#pragma unroll
    for (int i = 0; i < 4; ++i) {
      int row0 = r0 + wm + i * 16 + quad * 4;
#pragma unroll
      for (int r = 0; r < 4; ++r) {
        float v = acc[i][j][r] + bias;
        float g = 0.5f * v * (1.0f + erff(v * 0.70710678118654752f));
        hmat[(size_t)(row0 + r) * HID + col] = f2bf(g);
      }
    }
  }
}

// FFN2: ffn_h(16384x1024) @ w2T + b2 -> x4 (B,n,C) bf16
__global__ __launch_bounds__(256) void k_gemm_ffn2(const u16* __restrict__ a,
                                                   const u16* __restrict__ wT,
                                                   const float* __restrict__ b2,
                                                   u16* __restrict__ x4) {
  GEMM_PROLOGUE(HID, a, wT)
#pragma unroll
  for (int j = 0; j < 4; ++j) {
    int col = c0 + wn + j * 16 + l16;
    float bias = b2[col];
#pragma unroll
    for (int i = 0; i < 4; ++i) {
      int row0 = r0 + wm + i * 16 + quad * 4;
#pragma unroll
      for (int r = 0; r < 4; ++r)
        x4[(size_t)(row0 + r) * CH + col] = f2bf(acc[i][j][r] + bias);
    }
  }
}

// ---------------------------------------------------------------------------
// Flash attention, fixed-max softmax (scores bounded; exp2 safe in fp32).
// grid: 2048, block 256
// ---------------------------------------------------------------------------
__global__ __launch_bounds__(256) void k_attn(const u16* __restrict__ q,
                                              const u16* __restrict__ k,
                                              const u16* __restrict__ vT,
                                              const u16* __restrict__ biasB,
                                              u16* __restrict__ ao) {
  __shared__ u16 Ks[256][40];   // permuted rows; stride 80 B
  __shared__ u16 Vt[32][264];   // [d][j], stride 528 B
  __shared__ u16 Ps[4][16][40]; // per-wave P staging (written as b32)
  const int tid = threadIdx.x;
  const int wave = tid >> 6, lane = tid & 63;
  const int quad = lane >> 4, l16 = lane & 15;
  const int bh = blockIdx.x >> 4, qt = blockIdx.x & 15;
  const int h = bh & 7, bb = bh >> 3;
  const int i0 = qt * 64 + wave * 16;

  short8 aq = *(const short8*)(q + ((size_t)bh * NT + i0 + l16) * DH + quad * 8);
  const u16* bias_h = biasB + (size_t)h * 1048576 + (size_t)(i0 + quad * 4) * 2;

  float l_loc[4] = {0.f, 0.f, 0.f, 0.f};
  f32x4 acc0 = 0.f, acc1 = 0.f;

  for (int chunk = 0; chunk < 4; ++chunk) {
    __syncthreads();
    const int rbase = chunk * 256;
    {
      const int srow = tid >> 3, sdd = (tid & 7) * 4;
#pragma unroll
      for (int it = 0; it < 8; ++it) {
        int rl = it * 32 + srow;
        int rowL = (rl & ~31) | ((rl & 31) >> 1) | ((rl & 1) << 4);
        US4 kv = *(const US4*)(k + ((size_t)bh * NT + rbase + rl) * DH + sdd);
        *(US4*)&Ks[rowL][sdd] = kv;
      }
      const int j4 = (tid & 63) * 4;
#pragma unroll
      for (int it = 0; it < 8; ++it) {
        int d = it * 4 + wave;
        US4 vv = *(const US4*)(vT + ((size_t)bh * DH + d) * NT + rbase + j4);
        *(US4*)&Vt[d][j4] = vv;
      }
    }
    __syncthreads();

#pragma unroll 2
    for (int j0 = 0; j0 < 256; j0 += 32) {
      short8 bk0 = *(const short8*)&Ks[j0 + l16][quad * 8];
      short8 bk1 = *(const short8*)&Ks[j0 + 16 + l16][quad * 8];
      short8 be = *(const short8*)(bias_h +
                   ((size_t)((rbase + j0) >> 1) + l16) * 2048);
      const u16* bep = (const u16*)&be;
      f32x4 c0, c1;
#pragma unroll
      for (int r = 0; r < 4; ++r) {
        c0[r] = bf2f(bep[2 * r]);
        c1[r] = bf2f(bep[2 * r + 1]);
      }
      f32x4 s0 = MFMA(aq, bk0, c0);
      f32x4 s1 = MFMA(aq, bk1, c1);
      u32 packed[4];
#pragma unroll
      for (int r = 0; r < 4; ++r) {
        float p0 = fast_exp2(s0[r]);
        float p1 = fast_exp2(s1[r]);
        l_loc[r] += p0 + p1;
        packed[r] = pack_bf16_pair(p0, p1);
      }
      u32* psw = (u32*)&Ps[wave][0][0];
#pragma unroll
      for (int r = 0; r < 4; ++r) psw[(quad * 4 + r) * 20 + l16] = packed[r];
      short8 ap  = *(const short8*)&Ps[wave][l16][quad * 8];
      short8 bv0 = *(const short8*)&Vt[l16][j0 + quad * 8];
      short8 bv1 = *(const short8*)&Vt[16 + l16][j0 + quad * 8];
      acc0 = MFMA(ap, bv0, acc0);
      acc1 = MFMA(ap, bv1, acc1);
    }
  }
#pragma unroll
  for (int mask = 1; mask <= 8; mask <<= 1) {
#pragma unroll
    for (int r = 0; r < 4; ++r) l_loc[r] += __shfl_xor(l_loc[r], mask);
  }
#pragma unroll
  for (int r = 0; r < 4; ++r) {
    float inv = 1.0f / l_loc[r];
    int row = i0 + quad * 4 + r;
    u16* o = ao + ((size_t)bb * NT + row) * CH + h * DH;
    o[l16]      = f2bf(acc0[r] * inv);
    o[16 + l16] = f2bf(acc1[r] * inv);
  }
}

// ---------------------------------------------------------------------------
// LN2: x3 (B,n,C) bf16 rows contiguous -> x4ln (B,n,C) bf16. One wave per row.
// ---------------------------------------------------------------------------
__global__ __launch_bounds__(256) void k_ln2(const u16* __restrict__ x3,
                                             const float* __restrict__ w,
                                             const float* __restrict__ b,
                                             u16* __restrict__ x4ln) {
  const int wave = threadIdx.x >> 6, lane = threadIdx.x & 63;
  const size_t row = (size_t)blockIdx.x * 4 + wave;
  US4 u = *(const US4*)(x3 + row * CH + lane * 4);
  float v0 = bf2f(u.x), v1 = bf2f(u.y), v2 = bf2f(u.z), v3 = bf2f(u.w);
  float s = v0 + v1 + v2 + v3;
  float qq = v0 * v0 + v1 * v1 + v2 * v2 + v3 * v3;
#pragma unroll
  for (int mask = 1; mask <= 32; mask <<= 1) {
    s += __shfl_xor(s, mask);
    qq += __shfl_xor(qq, mask);
  }
  float mu = s * (1.f / CH);
  float var = qq * (1.f / CH) - mu * mu;
  float rs = rsqrtf(fmaxf(var, 0.f) + LN_EPS);
  F4 uw = *(const F4*)(w + lane * 4);
  F4 ub = *(const F4*)(b + lane * 4);
  US4 o;
  o.x = f2bf((v0 - mu) * rs * uw.x + ub.x);
  o.y = f2bf((v1 - mu) * rs * uw.y + ub.y);
  o.z = f2bf((v2 - mu) * rs * uw.z + ub.z);
  o.w = f2bf((v3 - mu) * rs * uw.w + ub.w);
  *(US4*)(x4ln + row * CH + lane * 4) = o;
}

// ---------------------------------------------------------------------------
// Final: out[b][c][pos] = x3[b][pos][c] + x4[b][pos][c]  (fp32 out)
// ---------------------------------------------------------------------------
__global__ __launch_bounds__(256) void k_add_t(const u16* __restrict__ x3,
                                               const u16* __restrict__ x4,
                                               float* __restrict__ out) {
  __shared__ float tl[64][66];
  const int t = threadIdx.x;
  const int bb = blockIdx.x >> 6;
  const int pb = (blockIdx.x >> 2) & 15, cb = blockIdx.x & 3;
  const int pos0 = pb * 64, c0 = cb * 64;
#pragma unroll
  for (int it = 0; it < 16; ++it) {
    int c_l = t & 63, p_l = it * 4 + (t >> 6);
    size_t ro = ((size_t)bb * NT + pos0 + p_l) * CH + c0 + c_l;
    tl[p_l][c_l] = bf2f(x3[ro]) + bf2f(x4[ro]);
  }
  __syncthreads();
#pragma unroll
  for (int it = 0; it < 16; ++it) {
    int p_l = t & 63, c_l = it * 4 + (t >> 6);
    out[((size_t)bb * CH + c0 + c_l) * NT + pos0 + p_l] = tl[p_l][c_l];
  }
}

// ---------------------------------------------------------------------------
// Launch
// ---------------------------------------------------------------------------
extern "C" void kernel_launch(void* const* d_in, const int* in_sizes, int n_in,
                              void* d_out, int out_size, void* d_ws, size_t ws_size,
                              hipStream_t stream) {
  const float* x       = (const float*)d_in[0];
  const float* qkv_w   = (const float*)d_in[1];
  const float* proj_w  = (const float*)d_in[2];
  const float* proj_b  = (const float*)d_in[3];
  const float* ffn_w1  = (const float*)d_in[4];
  const float* ffn_b1  = (const float*)d_in[5];
  const float* ffn_w2  = (const float*)d_in[6];
  const float* ffn_b2  = (const float*)d_in[7];
  const float* norm1_w = (const float*)d_in[8];
  const float* norm1_b = (const float*)d_in[9];
  const float* norm2_w = (const float*)d_in[10];
  const float* norm2_b = (const float*)d_in[11];
  const float* btab    = (const float*)d_in[12];
  const int* rel       = (const int*)d_in[13];
  float* out = (float*)d_out;

  char* ws = (char*)d_ws;
  size_t off = 0;
  auto alloc = [&](size_t bytes) { char* p = ws + off; off += bytes; return p; };
  u16* qkv_wT  = (u16*)alloc((size_t)768 * 256 * 2);
  u16* proj_wT = (u16*)alloc((size_t)256 * 256 * 2);
  u16* w1T     = (u16*)alloc((size_t)1024 * 256 * 2);
  u16* w2T     = (u16*)alloc((size_t)256 * 1024 * 2);
  u16* biasB   = (u16*)alloc((size_t)NH * NT * NT * 2);   // 16.78 MB
  u16* qm      = (u16*)alloc((size_t)MROWS * CH * 2);     // 8.39 MB
  u16* km      = (u16*)alloc((size_t)MROWS * CH * 2);     // 8.39 MB
  u16* vm      = (u16*)alloc((size_t)MROWS * CH * 2);     // 8.39 MB (as vT)
  u16* bufX    = (u16*)alloc((size_t)MROWS * CH * 2);     // 8.39 MB
  u16* x3      = (u16*)alloc((size_t)MROWS * CH * 2);     // 8.39 MB
  u16* ffn_h = biasB;  // overlay (dead after attention)
  u16* x4ln  = vm;     // overlay (dead after attention)
  u16* x1 = bufX;
  u16* ao = bufX;
  u16* x4 = bufX;
  (void)ws_size; (void)in_sizes; (void)n_in; (void)out_size;

  k_transpose<<<dim3(4, 12), 256, 0, stream>>>(qkv_w, qkv_wT, 256, 768);
  k_transpose<<<dim3(4, 4), 256, 0, stream>>>(proj_w, proj_wT, 256, 256);
  k_transpose<<<dim3(4, 16), 256, 0, stream>>>(ffn_w1, w1T, 256, 1024);
  k_transpose<<<dim3(16, 4), 256, 0, stream>>>(ffn_w2, w2T, 1024, 256);
  k_prep_bias<<<256, 256, 0, stream>>>(btab, rel, biasB);
  k_ln1<<<BATCH * 16, 256, 0, stream>>>(x, norm1_w, norm1_b, x1);
  k_gemm_qkv<<<dim3(MROWS / 128, 6), 256, 0, stream>>>(x1, qkv_wT, qm, km, vm);
  k_attn<<<BATCH * NH * 16, 256, 0, stream>>>(qm, km, vm, biasB, ao);
  k_gemm_proj<<<dim3(MROWS / 128, 2), 256, 0, stream>>>(ao, proj_wT, proj_b, x, x3);
  k_ln2<<<MROWS / 4, 256, 0, stream>>>(x3, norm2_w, norm2_b, x4ln);
  k_gemm_ffn1<<<dim3(MROWS / 128, 8), 256, 0, stream>>>(x4ln, w1T, ffn_b1, ffn_h);
  k_gemm_ffn2<<<dim3(MROWS / 128, 2), 256, 0, stream>>>(ffn_h, w2T, ffn_b2, x4);
  k_add_t<<<BATCH * 16 * 4, 256, 0, stream>>>(x3, x4, out);
}

// Round 7
// 266.496 us; speedup vs baseline: 1.9669x; 1.0202x over previous
//
#include <hip/hip_runtime.h>
#include <math.h>

// ---------------------------------------------------------------------------
// Problem constants
// ---------------------------------------------------------------------------
#define BATCH 16
#define CH    256          // channels C
#define NT    1024         // tokens n = 32*32
#define NH    8            // heads
#define DH    32           // dim_head
#define HID   1024         // ffn hidden
#define MROWS (BATCH * NT) // 16384 rows for all GEMMs
#define LN_EPS 1e-5f

typedef unsigned short u16;
typedef unsigned int u32;
typedef __attribute__((ext_vector_type(8))) short short8;   // 8 x bf16 (4 VGPRs)
typedef __attribute__((ext_vector_type(4))) short short4v;  // 4 x bf16 (2 VGPRs)
typedef __attribute__((ext_vector_type(4))) float f32x4;

struct __align__(8) US4 { u16 x, y, z, w; };
struct __align__(16) F4 { float x, y, z, w; };

#define MFMA(a, b, c) __builtin_amdgcn_mfma_f32_16x16x32_bf16((a), (b), (c), 0, 0, 0)
// v_mfma_f32_16x16x16_bf16 (gfx90a-lineage "_1k" builtin name; on gfx950 per
// cdna4_isa.md §10: A/B = 4 bf16 per lane (2 VGPRs), C/D = 4 f32).
// Defined unconditionally: __has_builtin is false on the HIP *host* pass.
#define MFMA16(a, b, c) __builtin_amdgcn_mfma_f32_16x16x16bf16_1k((a), (b), (c), 0, 0, 0)

#define LOG2E 1.4426950408889634f
#define QSCALE (0.17677669529663687f * 1.4426950408889634f)  // scale * log2e

__device__ __forceinline__ float bf2f(u16 u) {
  union { unsigned int i; float f; } v; v.i = ((unsigned int)u) << 16; return v.f;
}
__device__ __forceinline__ u16 f2bf(float f) {
  union { float f; unsigned int i; } v; v.f = f;
  unsigned int i = v.i;
  return (u16)((i + 0x7fffu + ((i >> 16) & 1u)) >> 16);  // RNE
}
__device__ __forceinline__ u32 pack_bf16_pair(float lo, float hi) {
  union { float f; u32 i; } a, b; a.f = lo; b.f = hi;
#if defined(__HIP_DEVICE_COMPILE__)
  return __builtin_amdgcn_perm(b.i, a.i, 0x07060302u);
#else
  return (b.i & 0xFFFF0000u) | (a.i >> 16);
#endif
}
__device__ __forceinline__ float fast_exp2(float x) {
  return exp2f(x);  // lowers to v_exp_f32 with -O3 on gfx950
}
// async global->LDS, 16 B per lane; LDS dest = uniform base + lane*16
__device__ __forceinline__ void llds16(const u16* g, u16* l) {
  __builtin_amdgcn_global_load_lds(
      (const __attribute__((address_space(1))) u32*)g,
      (__attribute__((address_space(3))) u32*)l, 16, 0, 0);
}

// ---------------------------------------------------------------------------
// Weight transpose + fp32->bf16: in (K x N) fp32 -> out (N x K) bf16
// ---------------------------------------------------------------------------
__global__ __launch_bounds__(256) void k_transpose(const float* __restrict__ in,
                                                   u16* __restrict__ out,
                                                   int K, int N) {
  __shared__ u16 tl[64][66];
  const int t = threadIdx.x;
  const int kb = blockIdx.x * 64, nb = blockIdx.y * 64;
#pragma unroll
  for (int it = 0; it < 16; ++it) {
    int n_l = t & 63, k_l = it * 4 + (t >> 6);
    tl[k_l][n_l] = f2bf(in[(size_t)(kb + k_l) * N + nb + n_l]);
  }
  __syncthreads();
#pragma unroll
  for (int it = 0; it < 16; ++it) {
    int k_l = t & 63, n_l = it * 4 + (t >> 6);
    out[(size_t)(nb + n_l) * K + kb + k_l] = tl[k_l][n_l];
  }
}

// ---------------------------------------------------------------------------
// Bias pre-gather, scaled by log2e, layout [h][jt][i][j']  (jt=j>>5, j'=j&31)
// -> the S^T C-operand for tile (i0, jg) is two coalesced b64s per lane.
// grid: 256 (32 jt x 8 i-slices), block 256
// ---------------------------------------------------------------------------
__global__ __launch_bounds__(256) void k_prep_bias(const float* __restrict__ table,
                                                   const int* __restrict__ rel,
                                                   u16* __restrict__ biasL) {
  const int t = threadIdx.x;
  const int jt = blockIdx.x & 31, isl = blockIdx.x >> 5;
  const int jp = t & 31, io = t >> 5;
  for (int ib = isl * 128; ib < isl * 128 + 128; ib += 8) {
    int i = ib + io;
    int idx = rel[(size_t)i * NT + jt * 32 + jp];
#pragma unroll
    for (int h = 0; h < NH; ++h) {
      biasL[(((size_t)h * 32 + jt) * 1024 + i) * 32 + jp] =
          f2bf(table[(size_t)idx * NH + h] * LOG2E);
    }
  }
}

// ---------------------------------------------------------------------------
// LN1 fused with (B,C,n) -> (B,n,C) transpose + fp32->bf16.
// ---------------------------------------------------------------------------
__global__ __launch_bounds__(256) void k_ln1(const float* __restrict__ x,
                                             const float* __restrict__ w,
                                             const float* __restrict__ b,
                                             u16* __restrict__ x1) {
  __shared__ u16 tile[CH][68];
  __shared__ float red_s[4][64], red_q[4][64], mu_s[64], rs_s[64];
  const int t = threadIdx.x;
  const int bb = blockIdx.x >> 4, pb = blockIdx.x & 15;
  const int pos0 = pb * 64;
#pragma unroll
  for (int it = 0; it < 16; ++it) {
    int c = it * 16 + (t >> 4), p4 = (t & 15) * 4;
    F4 v = *(const F4*)(x + ((size_t)bb * CH + c) * NT + pos0 + p4);
    US4 o; o.x = f2bf(v.x); o.y = f2bf(v.y); o.z = f2bf(v.z); o.w = f2bf(v.w);
    *(US4*)&tile[c][p4] = o;
  }
  __syncthreads();
  {
    int pos = t & 63, g = t >> 6;
    float s = 0.f, q = 0.f;
#pragma unroll 8
    for (int cc = 0; cc < 64; ++cc) {
      float v = bf2f(tile[g * 64 + cc][pos]);
      s += v; q += v * v;
    }
    red_s[g][pos] = s; red_q[g][pos] = q;
  }
  __syncthreads();
  if (t < 64) {
    float s = red_s[0][t] + red_s[1][t] + red_s[2][t] + red_s[3][t];
    float q = red_q[0][t] + red_q[1][t] + red_q[2][t] + red_q[3][t];
    float mu = s * (1.f / CH);
    float var = q * (1.f / CH) - mu * mu;
    mu_s[t] = mu;
    rs_s[t] = rsqrtf(fmaxf(var, 0.f) + LN_EPS);
  }
  __syncthreads();
  {
    const int c = t;
    const float wv = w[c], bv = b[c];
    for (int pos = 0; pos < 64; ++pos) {
      float v = (bf2f(tile[c][pos]) - mu_s[pos]) * rs_s[pos] * wv + bv;
      x1[((size_t)bb * NT + pos0 + pos) * CH + c] = f2bf(v);
    }
  }
}

// ---------------------------------------------------------------------------
// m97-style LDS-staged GEMM core: 128x128 block tile, BK=32, 4 waves x 64x64.
// ---------------------------------------------------------------------------
template <int K>
__device__ __forceinline__ void gemm128(const u16* __restrict__ A,
                                        const u16* __restrict__ Bt,
                                        int r0, int c0, int tid,
                                        u16* lA, u16* lB,
                                        f32x4 acc[4][4]) {
  const int wave = tid >> 6, lane = tid & 63;
  const int wm = (wave >> 1) * 64, wn = (wave & 1) * 64;
  const int l16 = lane & 15, quad = lane >> 4;
  const int srow = lane >> 2;
  const int scol = (lane & 3) * 8;
  const u16* gA0 = A + (size_t)(r0 + wave * 16 + srow) * K + scol;
  const u16* gA1 = A + (size_t)(r0 + wave * 16 + 64 + srow) * K + scol;
  const u16* gB0 = Bt + (size_t)(c0 + wave * 16 + srow) * K + scol;
  const u16* gB1 = Bt + (size_t)(c0 + wave * 16 + 64 + srow) * K + scol;
  u16* lA0 = lA + (wave * 16) * 32;
  u16* lA1 = lA + (wave * 16 + 64) * 32;
  u16* lB0 = lB + (wave * 16) * 32;
  u16* lB1 = lB + (wave * 16 + 64) * 32;
  for (int k0 = 0; k0 < K; k0 += 32) {
    __syncthreads();
    llds16(gA0 + k0, lA0);
    llds16(gA1 + k0, lA1);
    llds16(gB0 + k0, lB0);
    llds16(gB1 + k0, lB1);
    __syncthreads();
    short8 af[4], bf[4];
#pragma unroll
    for (int i = 0; i < 4; ++i)
      af[i] = *(const short8*)&lA[(wm + i * 16 + l16) * 32 + quad * 8];
#pragma unroll
    for (int j = 0; j < 4; ++j)
      bf[j] = *(const short8*)&lB[(wn + j * 16 + l16) * 32 + quad * 8];
#pragma unroll
    for (int i = 0; i < 4; ++i)
#pragma unroll
      for (int j = 0; j < 4; ++j)
        acc[i][j] = MFMA(af[i], bf[j], acc[i][j]);
  }
}

#define GEMM_PROLOGUE(KVAL, APTR, BPTR)                                  \
  __shared__ __align__(16) u16 lA[128 * 32];                             \
  __shared__ __align__(16) u16 lB[128 * 32];                             \
  const int tid = threadIdx.x;                                           \
  const int wave = tid >> 6, lane = tid & 63;                            \
  const int wm = (wave >> 1) * 64, wn = (wave & 1) * 64;                 \
  const int l16 = lane & 15, quad = lane >> 4;                           \
  const int r0 = blockIdx.x * 128, c0 = blockIdx.y * 128;                \
  f32x4 acc[4][4];                                                       \
  _Pragma("unroll") for (int i = 0; i < 4; ++i)                          \
  _Pragma("unroll") for (int j = 0; j < 4; ++j) acc[i][j] = 0.f;         \
  gemm128<KVAL>(APTR, BPTR, r0, c0, tid, lA, lB, acc);

// QKV: x1(16384x256) @ qkv_wT(768x256)^T -> q (scaled), k, vT (B,H,d,n)
__global__ __launch_bounds__(256) void k_gemm_qkv(const u16* __restrict__ x1,
                                                  const u16* __restrict__ wT,
                                                  u16* __restrict__ q,
                                                  u16* __restrict__ k,
                                                  u16* __restrict__ vT) {
  GEMM_PROLOGUE(CH, x1, wT)
#pragma unroll
  for (int j = 0; j < 4; ++j) {
    int col = c0 + wn + j * 16 + l16;
    int which = col >> 8, rem = col & 255, h = rem >> 5, dd = rem & 31;
#pragma unroll
    for (int i = 0; i < 4; ++i) {
      int row0 = r0 + wm + i * 16 + quad * 4;
      int bb = row0 >> 10, pos = row0 & 1023;
      if (which == 2) {
        US4 o;
        o.x = f2bf(acc[i][j][0]); o.y = f2bf(acc[i][j][1]);
        o.z = f2bf(acc[i][j][2]); o.w = f2bf(acc[i][j][3]);
        *(US4*)(vT + (((size_t)bb * NH + h) * DH + dd) * NT + pos) = o;
      } else {
        u16* dst = (which == 0) ? q : k;
        float mul = (which == 0) ? QSCALE : 1.0f;
#pragma unroll
        for (int r = 0; r < 4; ++r)
          dst[(((size_t)bb * NH + h) * NT + pos + r) * DH + dd] =
              f2bf(acc[i][j][r] * mul);
      }
    }
  }
}

// PROJ: attn_out(16384x256) @ proj_wT + proj_b + x^T -> x3 (B,n,C) bf16
__global__ __launch_bounds__(256) void k_gemm_proj(const u16* __restrict__ ao,
                                                   const u16* __restrict__ wT,
                                                   const float* __restrict__ pb,
                                                   const float* __restrict__ x,
                                                   u16* __restrict__ x3) {
  GEMM_PROLOGUE(CH, ao, wT)
#pragma unroll
  for (int j = 0; j < 4; ++j) {
    int col = c0 + wn + j * 16 + l16;
    float bias = pb[col];
#pragma unroll
    for (int i = 0; i < 4; ++i) {
      int row0 = r0 + wm + i * 16 + quad * 4;
      int bb = row0 >> 10, pos = row0 & 1023;
#pragma unroll
      for (int r = 0; r < 4; ++r) {
        float val = acc[i][j][r] + bias + x[((size_t)bb * CH + col) * NT + pos + r];
        x3[(size_t)(row0 + r) * CH + col] = f2bf(val);
      }
    }
  }
}

// FFN1: x4ln(16384x256) @ w1T + b1, exact GELU -> ffn_h (16384x1024) bf16
__global__ __launch_bounds__(256) void k_gemm_ffn1(const u16* __restrict__ a,
                                                   const u16* __restrict__ wT,
                                                   const float* __restrict__ b1,
                                                   u16* __restrict__ hmat) {
  GEMM_PROLOGUE(CH, a, wT)
#pragma unroll
  for (int j = 0; j < 4; ++j) {
    int col = c0 + wn + j * 16 + l16;
    float bias = b1[col];
#pragma unroll
    for (int i = 0; i < 4; ++i) {
      int row0 = r0 + wm + i * 16 + quad * 4;
#pragma unroll
      for (int r = 0; r < 4; ++r) {
        float v = acc[i][j][r] + bias;
        float g = 0.5f * v * (1.0f + erff(v * 0.70710678118654752f));
        hmat[(size_t)(row0 + r) * HID + col] = f2bf(g);
      }
    }
  }
}

// FFN2: ffn_h(16384x1024) @ w2T + b2 -> x4 (B,n,C) bf16
__global__ __launch_bounds__(256) void k_gemm_ffn2(const u16* __restrict__ a,
                                                   const u16* __restrict__ wT,
                                                   const float* __restrict__ b2,
                                                   u16* __restrict__ x4) {
  GEMM_PROLOGUE(HID, a, wT)
#pragma unroll
  for (int j = 0; j < 4; ++j) {
    int col = c0 + wn + j * 16 + l16;
    float bias = b2[col];
#pragma unroll
    for (int i = 0; i < 4; ++i) {
      int row0 = r0 + wm + i * 16 + quad * 4;
#pragma unroll
      for (int r = 0; r < 4; ++r)
        x4[(size_t)(row0 + r) * CH + col] = f2bf(acc[i][j][r] + bias);
    }
  }
}

// ---------------------------------------------------------------------------
// Flash attention v2: S^T = K.Q^T (A=K-frag, B=q-frag), so P lands per-lane as
// P[q=l16][j=quad*4+r] == the A-fragment of mfma_16x16x16 -> PV needs NO LDS
// round-trip (in-register pack, 4 MFMA16 per 32-key tile). Fixed-max softmax.
// grid: 2048, block 256. LDS 37.4 KB -> 4 blocks/CU.
// ---------------------------------------------------------------------------
__global__ __launch_bounds__(256) void k_attn(const u16* __restrict__ q,
                                              const u16* __restrict__ k,
                                              const u16* __restrict__ vT,
                                              const u16* __restrict__ biasL,
                                              u16* __restrict__ ao) {
  __shared__ u16 Ks[256][40];   // [j][d], stride 80 B
  __shared__ u16 Vt[32][264];   // [d][j], stride 528 B
  const int tid = threadIdx.x;
  const int wave = tid >> 6, lane = tid & 63;
  const int quad = lane >> 4, l16 = lane & 15;
  const int bh = blockIdx.x >> 4, qt = blockIdx.x & 15;
  const int h = bh & 7, bb = bh >> 3;
  const int i0 = qt * 64 + wave * 16;

  // Q fragment: content Q[q=i0+l16][d=quad*8+i] -- used as the B operand
  short8 aq = *(const short8*)(q + ((size_t)bh * NT + i0 + l16) * DH + quad * 8);
  // bias lane base: [h][jt=0][i=i0+l16][j'=quad*4]
  const u16* bias_base =
      biasL + (((size_t)h * 32) * 1024 + (i0 + l16)) * 32 + quad * 4;

  float l_loc = 0.f;                 // partial softmax denom for q=l16
  f32x4 accd0 = 0.f, accd1 = 0.f;    // O[q=quad*4+r][d=l16 / 16+l16]

  for (int chunk = 0; chunk < 4; ++chunk) {
    __syncthreads();
    const int rbase = chunk * 256;
    {
      // K: natural rows
      const int srow = tid >> 3, sdd = (tid & 7) * 4;
#pragma unroll
      for (int it = 0; it < 8; ++it) {
        int rl = it * 32 + srow;
        US4 kv = *(const US4*)(k + ((size_t)bh * NT + rbase + rl) * DH + sdd);
        *(US4*)&Ks[rl][sdd] = kv;
      }
      // V: row copies from vT (d-major), contiguous
      const int j4 = (tid & 63) * 4;
#pragma unroll
      for (int it = 0; it < 8; ++it) {
        int d = it * 4 + wave;
        US4 vv = *(const US4*)(vT + ((size_t)bh * DH + d) * NT + rbase + j4);
        *(US4*)&Vt[d][j4] = vv;
      }
    }
    __syncthreads();

#pragma unroll 2
    for (int j0 = 0; j0 < 256; j0 += 32) {
      const int jt = (rbase + j0) >> 5;
      // bias C-operands: two b64s, full-line coalesced across the wave
      const u16* bl = bias_base + (size_t)jt * 32768;
      US4 b0 = *(const US4*)bl;
      US4 b1 = *(const US4*)(bl + 16);
      f32x4 cc0, cc1;
      cc0[0] = bf2f(b0.x); cc0[1] = bf2f(b0.y);
      cc0[2] = bf2f(b0.z); cc0[3] = bf2f(b0.w);
      cc1[0] = bf2f(b1.x); cc1[1] = bf2f(b1.y);
      cc1[2] = bf2f(b1.z); cc1[3] = bf2f(b1.w);
      // K fragments (A operand): K[j = j0+s*16+l16][d = quad*8+i]
      short8 ak0 = *(const short8*)&Ks[j0 + l16][quad * 8];
      short8 ak1 = *(const short8*)&Ks[j0 + 16 + l16][quad * 8];
      f32x4 s0 = MFMA(ak0, aq, cc0);  // S^T[j=quad*4+r][q=l16], keys j0..j0+15
      f32x4 s1 = MFMA(ak1, aq, cc1);  // keys j0+16..j0+31
      float p00 = fast_exp2(s0[0]), p01 = fast_exp2(s0[1]);
      float p02 = fast_exp2(s0[2]), p03 = fast_exp2(s0[3]);
      float p10 = fast_exp2(s1[0]), p11 = fast_exp2(s1[1]);
      float p12 = fast_exp2(s1[2]), p13 = fast_exp2(s1[3]);
      l_loc += ((p00 + p01) + (p02 + p03)) + ((p10 + p11) + (p12 + p13));
      // pack P as MFMA16 A-frags (k = quad*4 + i)
      union { u32 u[2]; short4v s; } pa0, pa1;
      pa0.u[0] = pack_bf16_pair(p00, p01);
      pa0.u[1] = pack_bf16_pair(p02, p03);
      pa1.u[0] = pack_bf16_pair(p10, p11);
      pa1.u[1] = pack_bf16_pair(p12, p13);
      // V B-frags: V[j = jsub + quad*4 + i][d = l16 / 16+l16] from Vt[d][j]
      short4v vb00 = *(const short4v*)&Vt[l16][j0 + quad * 4];
      short4v vb10 = *(const short4v*)&Vt[l16][j0 + 16 + quad * 4];
      short4v vb01 = *(const short4v*)&Vt[16 + l16][j0 + quad * 4];
      short4v vb11 = *(const short4v*)&Vt[16 + l16][j0 + 16 + quad * 4];
      accd0 = MFMA16(pa0.s, vb00, accd0);
      accd1 = MFMA16(pa0.s, vb01, accd1);
      accd0 = MFMA16(pa1.s, vb10, accd0);
      accd1 = MFMA16(pa1.s, vb11, accd1);
    }
  }
  // softmax denom: sum quads (j-partials) -> all lanes have l(q=l16)
  l_loc += __shfl_xor(l_loc, 16);
  l_loc += __shfl_xor(l_loc, 32);
#pragma unroll
  for (int r = 0; r < 4; ++r) {
    float lr = __shfl(l_loc, quad * 4 + r);  // l for q = quad*4+r
    float inv = 1.0f / lr;
    int row = i0 + quad * 4 + r;
    u16* o = ao + ((size_t)bb * NT + row) * CH + h * DH;
    o[l16]      = f2bf(accd0[r] * inv);
    o[16 + l16] = f2bf(accd1[r] * inv);
  }
}

// ---------------------------------------------------------------------------
// LN2: x3 (B,n,C) bf16 rows contiguous -> x4ln (B,n,C) bf16. One wave per row.
// ---------------------------------------------------------------------------
__global__ __launch_bounds__(256) void k_ln2(const u16* __restrict__ x3,
                                             const float* __restrict__ w,
                                             const float* __restrict__ b,
                                             u16* __restrict__ x4ln) {
  const int wave = threadIdx.x >> 6, lane = threadIdx.x & 63;
  const size_t row = (size_t)blockIdx.x * 4 + wave;
  US4 u = *(const US4*)(x3 + row * CH + lane * 4);
  float v0 = bf2f(u.x), v1 = bf2f(u.y), v2 = bf2f(u.z), v3 = bf2f(u.w);
  float s = v0 + v1 + v2 + v3;
  float qq = v0 * v0 + v1 * v1 + v2 * v2 + v3 * v3;
#pragma unroll
  for (int mask = 1; mask <= 32; mask <<= 1) {
    s += __shfl_xor(s, mask);
    qq += __shfl_xor(qq, mask);
  }
  float mu = s * (1.f / CH);
  float var = qq * (1.f / CH) - mu * mu;
  float rs = rsqrtf(fmaxf(var, 0.f) + LN_EPS);
  F4 uw = *(const F4*)(w + lane * 4);
  F4 ub = *(const F4*)(b + lane * 4);
  US4 o;
  o.x = f2bf((v0 - mu) * rs * uw.x + ub.x);
  o.y = f2bf((v1 - mu) * rs * uw.y + ub.y);
  o.z = f2bf((v2 - mu) * rs * uw.z + ub.z);
  o.w = f2bf((v3 - mu) * rs * uw.w + ub.w);
  *(US4*)(x4ln + row * CH + lane * 4) = o;
}

// ---------------------------------------------------------------------------
// Final: out[b][c][pos] = x3[b][pos][c] + x4[b][pos][c]  (fp32 out)
// ---------------------------------------------------------------------------
__global__ __launch_bounds__(256) void k_add_t(const u16* __restrict__ x3,
                                               const u16* __restrict__ x4,
                                               float* __restrict__ out) {
  __shared__ float tl[64][66];
  const int t = threadIdx.x;
  const int bb = blockIdx.x >> 6;
  const int pb = (blockIdx.x >> 2) & 15, cb = blockIdx.x & 3;
  const int pos0 = pb * 64, c0 = cb * 64;
#pragma unroll
  for (int it = 0; it < 16; ++it) {
    int c_l = t & 63, p_l = it * 4 + (t >> 6);
    size_t ro = ((size_t)bb * NT + pos0 + p_l) * CH + c0 + c_l;
    tl[p_l][c_l] = bf2f(x3[ro]) + bf2f(x4[ro]);
  }
  __syncthreads();
#pragma unroll
  for (int it = 0; it < 16; ++it) {
    int p_l = t & 63, c_l = it * 4 + (t >> 6);
    out[((size_t)bb * CH + c0 + c_l) * NT + pos0 + p_l] = tl[p_l][c_l];
  }
}

// ---------------------------------------------------------------------------
// Launch
// ---------------------------------------------------------------------------
extern "C" void kernel_launch(void* const* d_in, const int* in_sizes, int n_in,
                              void* d_out, int out_size, void* d_ws, size_t ws_size,
                              hipStream_t stream) {
  const float* x       = (const float*)d_in[0];
  const float* qkv_w   = (const float*)d_in[1];
  const float* proj_w  = (const float*)d_in[2];
  const float* proj_b  = (const float*)d_in[3];
  const float* ffn_w1  = (const float*)d_in[4];
  const float* ffn_b1  = (const float*)d_in[5];
  const float* ffn_w2  = (const float*)d_in[6];
  const float* ffn_b2  = (const float*)d_in[7];
  const float* norm1_w = (const float*)d_in[8];
  const float* norm1_b = (const float*)d_in[9];
  const float* norm2_w = (const float*)d_in[10];
  const float* norm2_b = (const float*)d_in[11];
  const float* btab    = (const float*)d_in[12];
  const int* rel       = (const int*)d_in[13];
  float* out = (float*)d_out;

  char* ws = (char*)d_ws;
  size_t off = 0;
  auto alloc = [&](size_t bytes) { char* p = ws + off; off += bytes; return p; };
  u16* qkv_wT  = (u16*)alloc((size_t)768 * 256 * 2);
  u16* proj_wT = (u16*)alloc((size_t)256 * 256 * 2);
  u16* w1T     = (u16*)alloc((size_t)1024 * 256 * 2);
  u16* w2T     = (u16*)alloc((size_t)256 * 1024 * 2);
  u16* biasL   = (u16*)alloc((size_t)NH * NT * NT * 2);   // 16.78 MB
  u16* qm      = (u16*)alloc((size_t)MROWS * CH * 2);     // 8.39 MB
  u16* km      = (u16*)alloc((size_t)MROWS * CH * 2);     // 8.39 MB
  u16* vm      = (u16*)alloc((size_t)MROWS * CH * 2);     // 8.39 MB (as vT)
  u16* bufX    = (u16*)alloc((size_t)MROWS * CH * 2);     // 8.39 MB
  u16* x3      = (u16*)alloc((size_t)MROWS * CH * 2);     // 8.39 MB
  u16* ffn_h = biasL;  // overlay (dead after attention)
  u16* x4ln  = vm;     // overlay (dead after attention)
  u16* x1 = bufX;
  u16* ao = bufX;
  u16* x4 = bufX;
  (void)ws_size; (void)in_sizes; (void)n_in; (void)out_size;

  k_transpose<<<dim3(4, 12), 256, 0, stream>>>(qkv_w, qkv_wT, 256, 768);
  k_transpose<<<dim3(4, 4), 256, 0, stream>>>(proj_w, proj_wT, 256, 256);
  k_transpose<<<dim3(4, 16), 256, 0, stream>>>(ffn_w1, w1T, 256, 1024);
  k_transpose<<<dim3(16, 4), 256, 0, stream>>>(ffn_w2, w2T, 1024, 256);
  k_prep_bias<<<256, 256, 0, stream>>>(btab, rel, biasL);
  k_ln1<<<BATCH * 16, 256, 0, stream>>>(x, norm1_w, norm1_b, x1);
  k_gemm_qkv<<<dim3(MROWS / 128, 6), 256, 0, stream>>>(x1, qkv_wT, qm, km, vm);
  k_attn<<<BATCH * NH * 16, 256, 0, stream>>>(qm, km, vm, biasL, ao);
  k_gemm_proj<<<dim3(MROWS / 128, 2), 256, 0, stream>>>(ao, proj_wT, proj_b, x, x3);
  k_ln2<<<MROWS / 4, 256, 0, stream>>>(x3, norm2_w, norm2_b, x4ln);
  k_gemm_ffn1<<<dim3(MROWS / 128, 8), 256, 0, stream>>>(x4ln, w1T, ffn_b1, ffn_h);
  k_gemm_ffn2<<<dim3(MROWS / 128, 2), 256, 0, stream>>>(ffn_h, w2T, ffn_b2, x4);
  k_add_t<<<BATCH * 16 * 4, 256, 0, stream>>>(x3, x4, out);
}

// Round 8
// 253.786 us; speedup vs baseline: 2.0654x; 1.0501x over previous
//
#include <hip/hip_runtime.h>
#include <math.h>

// ---------------------------------------------------------------------------
// Problem constants
// ---------------------------------------------------------------------------
#define BATCH 16
#define CH    256          // channels C
#define NT    1024         // tokens n = 32*32
#define NH    8            // heads
#define DH    32           // dim_head
#define HID   1024         // ffn hidden
#define MROWS (BATCH * NT) // 16384 rows for all GEMMs
#define LN_EPS 1e-5f

typedef unsigned short u16;
typedef unsigned int u32;
typedef __attribute__((ext_vector_type(8))) short short8;   // 8 x bf16 (4 VGPRs)
typedef __attribute__((ext_vector_type(4))) short short4v;  // 4 x bf16 (2 VGPRs)
typedef __attribute__((ext_vector_type(4))) float f32x4;

struct __align__(8) US4 { u16 x, y, z, w; };
struct __align__(16) F4 { float x, y, z, w; };

#define MFMA(a, b, c) __builtin_amdgcn_mfma_f32_16x16x32_bf16((a), (b), (c), 0, 0, 0)
// v_mfma_f32_16x16x16_bf16 (gfx90a-lineage "_1k" builtin name); defined
// unconditionally: __has_builtin is false on the HIP *host* pass.
#define MFMA16(a, b, c) __builtin_amdgcn_mfma_f32_16x16x16bf16_1k((a), (b), (c), 0, 0, 0)

#define LOG2E 1.4426950408889634f
#define QSCALE (0.17677669529663687f * 1.4426950408889634f)  // scale * log2e

__device__ __forceinline__ float bf2f(u16 u) {
  union { unsigned int i; float f; } v; v.i = ((unsigned int)u) << 16; return v.f;
}
__device__ __forceinline__ u16 f2bf(float f) {
  union { float f; unsigned int i; } v; v.f = f;
  unsigned int i = v.i;
  return (u16)((i + 0x7fffu + ((i >> 16) & 1u)) >> 16);  // RNE
}
__device__ __forceinline__ u32 pack_bf16_pair(float lo, float hi) {
  union { float f; u32 i; } a, b; a.f = lo; b.f = hi;
#if defined(__HIP_DEVICE_COMPILE__)
  return __builtin_amdgcn_perm(b.i, a.i, 0x07060302u);
#else
  return (b.i & 0xFFFF0000u) | (a.i >> 16);
#endif
}
// RAW v_exp_f32 (quarter-rate transcendental, 1 inst). Round-7 lesson: plain
// exp2f lowers to the libm path (~8-10 VALU) and cost +20 us in k_attn.
__device__ __forceinline__ float fast_exp2(float x) {
#if defined(__HIP_DEVICE_COMPILE__)
  return __builtin_amdgcn_exp2f(x);
#else
  return exp2f(x);
#endif
}
// tanh-form GELU via raw exp2: g = x * t/(t+1), t = exp2(c*(x+0.044715 x^3)),
// c = 2*log2e*sqrt(2/pi). |g - gelu_exact| <~ 3e-3 (output tolerance 0.1).
__device__ __forceinline__ float fast_gelu(float x) {
  const float c = 2.0f * LOG2E * 0.7978845608028654f;
  float t = fast_exp2(c * (x + 0.044715f * x * x * x));
  return x * t / (t + 1.0f);
}
// async global->LDS, 16 B per lane; LDS dest = uniform base + lane*16
__device__ __forceinline__ void llds16(const u16* g, u16* l) {
  __builtin_amdgcn_global_load_lds(
      (const __attribute__((address_space(1))) u32*)g,
      (__attribute__((address_space(3))) u32*)l, 16, 0, 0);
}

// ---------------------------------------------------------------------------
// Weight transpose + fp32->bf16: in (K x N) fp32 -> out (N x K) bf16
// ---------------------------------------------------------------------------
__global__ __launch_bounds__(256) void k_transpose(const float* __restrict__ in,
                                                   u16* __restrict__ out,
                                                   int K, int N) {
  __shared__ u16 tl[64][66];
  const int t = threadIdx.x;
  const int kb = blockIdx.x * 64, nb = blockIdx.y * 64;
#pragma unroll
  for (int it = 0; it < 16; ++it) {
    int n_l = t & 63, k_l = it * 4 + (t >> 6);
    tl[k_l][n_l] = f2bf(in[(size_t)(kb + k_l) * N + nb + n_l]);
  }
  __syncthreads();
#pragma unroll
  for (int it = 0; it < 16; ++it) {
    int k_l = t & 63, n_l = it * 4 + (t >> 6);
    out[(size_t)(nb + n_l) * K + kb + k_l] = tl[k_l][n_l];
  }
}

// ---------------------------------------------------------------------------
// Bias pre-gather, scaled by log2e, layout [h][jt][i][j']  (jt=j>>5, j'=j&31)
// grid: 256 (32 jt x 8 i-slices), block 256
// ---------------------------------------------------------------------------
__global__ __launch_bounds__(256) void k_prep_bias(const float* __restrict__ table,
                                                   const int* __restrict__ rel,
                                                   u16* __restrict__ biasL) {
  const int t = threadIdx.x;
  const int jt = blockIdx.x & 31, isl = blockIdx.x >> 5;
  const int jp = t & 31, io = t >> 5;
  for (int ib = isl * 128; ib < isl * 128 + 128; ib += 8) {
    int i = ib + io;
    int idx = rel[(size_t)i * NT + jt * 32 + jp];
#pragma unroll
    for (int h = 0; h < NH; ++h) {
      biasL[(((size_t)h * 32 + jt) * 1024 + i) * 32 + jp] =
          f2bf(table[(size_t)idx * NH + h] * LOG2E);
    }
  }
}

// ---------------------------------------------------------------------------
// LN1 fused with (B,C,n) -> (B,n,C) transpose + fp32->bf16.
// ---------------------------------------------------------------------------
__global__ __launch_bounds__(256) void k_ln1(const float* __restrict__ x,
                                             const float* __restrict__ w,
                                             const float* __restrict__ b,
                                             u16* __restrict__ x1) {
  __shared__ u16 tile[CH][68];
  __shared__ float red_s[4][64], red_q[4][64], mu_s[64], rs_s[64];
  const int t = threadIdx.x;
  const int bb = blockIdx.x >> 4, pb = blockIdx.x & 15;
  const int pos0 = pb * 64;
#pragma unroll
  for (int it = 0; it < 16; ++it) {
    int c = it * 16 + (t >> 4), p4 = (t & 15) * 4;
    F4 v = *(const F4*)(x + ((size_t)bb * CH + c) * NT + pos0 + p4);
    US4 o; o.x = f2bf(v.x); o.y = f2bf(v.y); o.z = f2bf(v.z); o.w = f2bf(v.w);
    *(US4*)&tile[c][p4] = o;
  }
  __syncthreads();
  {
    int pos = t & 63, g = t >> 6;
    float s = 0.f, q = 0.f;
#pragma unroll 8
    for (int cc = 0; cc < 64; ++cc) {
      float v = bf2f(tile[g * 64 + cc][pos]);
      s += v; q += v * v;
    }
    red_s[g][pos] = s; red_q[g][pos] = q;
  }
  __syncthreads();
  if (t < 64) {
    float s = red_s[0][t] + red_s[1][t] + red_s[2][t] + red_s[3][t];
    float q = red_q[0][t] + red_q[1][t] + red_q[2][t] + red_q[3][t];
    float mu = s * (1.f / CH);
    float var = q * (1.f / CH) - mu * mu;
    mu_s[t] = mu;
    rs_s[t] = rsqrtf(fmaxf(var, 0.f) + LN_EPS);
  }
  __syncthreads();
  {
    const int c = t;
    const float wv = w[c], bv = b[c];
    for (int pos = 0; pos < 64; ++pos) {
      float v = (bf2f(tile[c][pos]) - mu_s[pos]) * rs_s[pos] * wv + bv;
      x1[((size_t)bb * NT + pos0 + pos) * CH + c] = f2bf(v);
    }
  }
}

// ---------------------------------------------------------------------------
// m97-style LDS-staged GEMM core: 128x128 block tile, BK=32, 4 waves x 64x64.
// ---------------------------------------------------------------------------
template <int K>
__device__ __forceinline__ void gemm128(const u16* __restrict__ A,
                                        const u16* __restrict__ Bt,
                                        int r0, int c0, int tid,
                                        u16* lA, u16* lB,
                                        f32x4 acc[4][4]) {
  const int wave = tid >> 6, lane = tid & 63;
  const int wm = (wave >> 1) * 64, wn = (wave & 1) * 64;
  const int l16 = lane & 15, quad = lane >> 4;
  const int srow = lane >> 2;
  const int scol = (lane & 3) * 8;
  const u16* gA0 = A + (size_t)(r0 + wave * 16 + srow) * K + scol;
  const u16* gA1 = A + (size_t)(r0 + wave * 16 + 64 + srow) * K + scol;
  const u16* gB0 = Bt + (size_t)(c0 + wave * 16 + srow) * K + scol;
  const u16* gB1 = Bt + (size_t)(c0 + wave * 16 + 64 + srow) * K + scol;
  u16* lA0 = lA + (wave * 16) * 32;
  u16* lA1 = lA + (wave * 16 + 64) * 32;
  u16* lB0 = lB + (wave * 16) * 32;
  u16* lB1 = lB + (wave * 16 + 64) * 32;
  for (int k0 = 0; k0 < K; k0 += 32) {
    __syncthreads();
    llds16(gA0 + k0, lA0);
    llds16(gA1 + k0, lA1);
    llds16(gB0 + k0, lB0);
    llds16(gB1 + k0, lB1);
    __syncthreads();
    short8 af[4], bf[4];
#pragma unroll
    for (int i = 0; i < 4; ++i)
      af[i] = *(const short8*)&lA[(wm + i * 16 + l16) * 32 + quad * 8];
#pragma unroll
    for (int j = 0; j < 4; ++j)
      bf[j] = *(const short8*)&lB[(wn + j * 16 + l16) * 32 + quad * 8];
#pragma unroll
    for (int i = 0; i < 4; ++i)
#pragma unroll
      for (int j = 0; j < 4; ++j)
        acc[i][j] = MFMA(af[i], bf[j], acc[i][j]);
  }
}

#define GEMM_PROLOGUE(KVAL, APTR, BPTR)                                  \
  __shared__ __align__(16) u16 lA[128 * 32];                             \
  __shared__ __align__(16) u16 lB[128 * 32];                             \
  const int tid = threadIdx.x;                                           \
  const int wave = tid >> 6, lane = tid & 63;                            \
  const int wm = (wave >> 1) * 64, wn = (wave & 1) * 64;                 \
  const int l16 = lane & 15, quad = lane >> 4;                           \
  const int r0 = blockIdx.x * 128, c0 = blockIdx.y * 128;                \
  f32x4 acc[4][4];                                                       \
  _Pragma("unroll") for (int i = 0; i < 4; ++i)                          \
  _Pragma("unroll") for (int j = 0; j < 4; ++j) acc[i][j] = 0.f;         \
  gemm128<KVAL>(APTR, BPTR, r0, c0, tid, lA, lB, acc);

// QKV: x1(16384x256) @ qkv_wT(768x256)^T -> q (scaled), k, vT (B,H,d,n)
__global__ __launch_bounds__(256) void k_gemm_qkv(const u16* __restrict__ x1,
                                                  const u16* __restrict__ wT,
                                                  u16* __restrict__ q,
                                                  u16* __restrict__ k,
                                                  u16* __restrict__ vT) {
  GEMM_PROLOGUE(CH, x1, wT)
#pragma unroll
  for (int j = 0; j < 4; ++j) {
    int col = c0 + wn + j * 16 + l16;
    int which = col >> 8, rem = col & 255, h = rem >> 5, dd = rem & 31;
#pragma unroll
    for (int i = 0; i < 4; ++i) {
      int row0 = r0 + wm + i * 16 + quad * 4;
      int bb = row0 >> 10, pos = row0 & 1023;
      if (which == 2) {
        US4 o;
        o.x = f2bf(acc[i][j][0]); o.y = f2bf(acc[i][j][1]);
        o.z = f2bf(acc[i][j][2]); o.w = f2bf(acc[i][j][3]);
        *(US4*)(vT + (((size_t)bb * NH + h) * DH + dd) * NT + pos) = o;
      } else {
        u16* dst = (which == 0) ? q : k;
        float mul = (which == 0) ? QSCALE : 1.0f;
#pragma unroll
        for (int r = 0; r < 4; ++r)
          dst[(((size_t)bb * NH + h) * NT + pos + r) * DH + dd] =
              f2bf(acc[i][j][r] * mul);
      }
    }
  }
}

// PROJ: attn_out(16384x256) @ proj_wT + proj_b + x^T -> x3 (B,n,C) bf16
__global__ __launch_bounds__(256) void k_gemm_proj(const u16* __restrict__ ao,
                                                   const u16* __restrict__ wT,
                                                   const float* __restrict__ pb,
                                                   const float* __restrict__ x,
                                                   u16* __restrict__ x3) {
  GEMM_PROLOGUE(CH, ao, wT)
#pragma unroll
  for (int j = 0; j < 4; ++j) {
    int col = c0 + wn + j * 16 + l16;
    float bias = pb[col];
#pragma unroll
    for (int i = 0; i < 4; ++i) {
      int row0 = r0 + wm + i * 16 + quad * 4;
      int bb = row0 >> 10, pos = row0 & 1023;
#pragma unroll
      for (int r = 0; r < 4; ++r) {
        float val = acc[i][j][r] + bias + x[((size_t)bb * CH + col) * NT + pos + r];
        x3[(size_t)(row0 + r) * CH + col] = f2bf(val);
      }
    }
  }
}

// FFN1: x4ln(16384x256) @ w1T + b1, fast GELU -> ffn_h (16384x1024) bf16
__global__ __launch_bounds__(256) void k_gemm_ffn1(const u16* __restrict__ a,
                                                   const u16* __restrict__ wT,
                                                   const float* __restrict__ b1,
                                                   u16* __restrict__ hmat) {
  GEMM_PROLOGUE(CH, a, wT)
#pragma unroll
  for (int j = 0; j < 4; ++j) {
    int col = c0 + wn + j * 16 + l16;
    float bias = b1[col];
#pragma unroll
    for (int i = 0; i < 4; ++i) {
      int row0 = r0 + wm + i * 16 + quad * 4;
#pragma unroll
      for (int r = 0; r < 4; ++r) {
        float v = acc[i][j][r] + bias;
        hmat[(size_t)(row0 + r) * HID + col] = f2bf(fast_gelu(v));
      }
    }
  }
}

// FFN2: ffn_h(16384x1024) @ w2T + b2 -> x4 (B,n,C) bf16
__global__ __launch_bounds__(256) void k_gemm_ffn2(const u16* __restrict__ a,
                                                   const u16* __restrict__ wT,
                                                   const float* __restrict__ b2,
                                                   u16* __restrict__ x4) {
  GEMM_PROLOGUE(HID, a, wT)
#pragma unroll
  for (int j = 0; j < 4; ++j) {
    int col = c0 + wn + j * 16 + l16;
    float bias = b2[col];
#pragma unroll
    for (int i = 0; i < 4; ++i) {
      int row0 = r0 + wm + i * 16 + quad * 4;
#pragma unroll
      for (int r = 0; r < 4; ++r)
        x4[(size_t)(row0 + r) * CH + col] = f2bf(acc[i][j][r] + bias);
    }
  }
}

// ---------------------------------------------------------------------------
// Flash attention v2: S^T = K.Q^T; P lands per-lane as the MFMA16 A-fragment
// -> PV with NO LDS round-trip. Fixed-max softmax, raw v_exp_f32.
// grid: 2048, block 256. LDS 37.4 KB.
// ---------------------------------------------------------------------------
__global__ __launch_bounds__(256) void k_attn(const u16* __restrict__ q,
                                              const u16* __restrict__ k,
                                              const u16* __restrict__ vT,
                                              const u16* __restrict__ biasL,
                                              u16* __restrict__ ao) {
  __shared__ u16 Ks[256][40];   // [j][d], stride 80 B
  __shared__ u16 Vt[32][264];   // [d][j], stride 528 B
  const int tid = threadIdx.x;
  const int wave = tid >> 6, lane = tid & 63;
  const int quad = lane >> 4, l16 = lane & 15;
  const int bh = blockIdx.x >> 4, qt = blockIdx.x & 15;
  const int h = bh & 7, bb = bh >> 3;
  const int i0 = qt * 64 + wave * 16;

  short8 aq = *(const short8*)(q + ((size_t)bh * NT + i0 + l16) * DH + quad * 8);
  const u16* bias_base =
      biasL + (((size_t)h * 32) * 1024 + (i0 + l16)) * 32 + quad * 4;

  float l_loc = 0.f;                 // partial softmax denom for q=l16
  f32x4 accd0 = 0.f, accd1 = 0.f;    // O[q=quad*4+r][d=l16 / 16+l16]

  for (int chunk = 0; chunk < 4; ++chunk) {
    __syncthreads();
    const int rbase = chunk * 256;
    {
      const int srow = tid >> 3, sdd = (tid & 7) * 4;
#pragma unroll
      for (int it = 0; it < 8; ++it) {
        int rl = it * 32 + srow;
        US4 kv = *(const US4*)(k + ((size_t)bh * NT + rbase + rl) * DH + sdd);
        *(US4*)&Ks[rl][sdd] = kv;
      }
      const int j4 = (tid & 63) * 4;
#pragma unroll
      for (int it = 0; it < 8; ++it) {
        int d = it * 4 + wave;
        US4 vv = *(const US4*)(vT + ((size_t)bh * DH + d) * NT + rbase + j4);
        *(US4*)&Vt[d][j4] = vv;
      }
    }
    __syncthreads();

#pragma unroll 2
    for (int j0 = 0; j0 < 256; j0 += 32) {
      const int jt = (rbase + j0) >> 5;
      const u16* bl = bias_base + (size_t)jt * 32768;
      US4 b0 = *(const US4*)bl;
      US4 b1 = *(const US4*)(bl + 16);
      f32x4 cc0, cc1;
      cc0[0] = bf2f(b0.x); cc0[1] = bf2f(b0.y);
      cc0[2] = bf2f(b0.z); cc0[3] = bf2f(b0.w);
      cc1[0] = bf2f(b1.x); cc1[1] = bf2f(b1.y);
      cc1[2] = bf2f(b1.z); cc1[3] = bf2f(b1.w);
      short8 ak0 = *(const short8*)&Ks[j0 + l16][quad * 8];
      short8 ak1 = *(const short8*)&Ks[j0 + 16 + l16][quad * 8];
      f32x4 s0 = MFMA(ak0, aq, cc0);  // S^T[j=quad*4+r][q=l16], keys j0..j0+15
      f32x4 s1 = MFMA(ak1, aq, cc1);  // keys j0+16..j0+31
      float p00 = fast_exp2(s0[0]), p01 = fast_exp2(s0[1]);
      float p02 = fast_exp2(s0[2]), p03 = fast_exp2(s0[3]);
      float p10 = fast_exp2(s1[0]), p11 = fast_exp2(s1[1]);
      float p12 = fast_exp2(s1[2]), p13 = fast_exp2(s1[3]);
      l_loc += ((p00 + p01) + (p02 + p03)) + ((p10 + p11) + (p12 + p13));
      union { u32 u[2]; short4v s; } pa0, pa1;
      pa0.u[0] = pack_bf16_pair(p00, p01);
      pa0.u[1] = pack_bf16_pair(p02, p03);
      pa1.u[0] = pack_bf16_pair(p10, p11);
      pa1.u[1] = pack_bf16_pair(p12, p13);
      short4v vb00 = *(const short4v*)&Vt[l16][j0 + quad * 4];
      short4v vb10 = *(const short4v*)&Vt[l16][j0 + 16 + quad * 4];
      short4v vb01 = *(const short4v*)&Vt[16 + l16][j0 + quad * 4];
      short4v vb11 = *(const short4v*)&Vt[16 + l16][j0 + 16 + quad * 4];
      accd0 = MFMA16(pa0.s, vb00, accd0);
      accd1 = MFMA16(pa0.s, vb01, accd1);
      accd0 = MFMA16(pa1.s, vb10, accd0);
      accd1 = MFMA16(pa1.s, vb11, accd1);
    }
  }
  l_loc += __shfl_xor(l_loc, 16);
  l_loc += __shfl_xor(l_loc, 32);
#pragma unroll
  for (int r = 0; r < 4; ++r) {
    float lr = __shfl(l_loc, quad * 4 + r);  // l for q = quad*4+r
    float inv = 1.0f / lr;
    int row = i0 + quad * 4 + r;
    u16* o = ao + ((size_t)bb * NT + row) * CH + h * DH;
    o[l16]      = f2bf(accd0[r] * inv);
    o[16 + l16] = f2bf(accd1[r] * inv);
  }
}

// ---------------------------------------------------------------------------
// LN2: x3 (B,n,C) bf16 rows contiguous -> x4ln (B,n,C) bf16. One wave per row.
// ---------------------------------------------------------------------------
__global__ __launch_bounds__(256) void k_ln2(const u16* __restrict__ x3,
                                             const float* __restrict__ w,
                                             const float* __restrict__ b,
                                             u16* __restrict__ x4ln) {
  const int wave = threadIdx.x >> 6, lane = threadIdx.x & 63;
  const size_t row = (size_t)blockIdx.x * 4 + wave;
  US4 u = *(const US4*)(x3 + row * CH + lane * 4);
  float v0 = bf2f(u.x), v1 = bf2f(u.y), v2 = bf2f(u.z), v3 = bf2f(u.w);
  float s = v0 + v1 + v2 + v3;
  float qq = v0 * v0 + v1 * v1 + v2 * v2 + v3 * v3;
#pragma unroll
  for (int mask = 1; mask <= 32; mask <<= 1) {
    s += __shfl_xor(s, mask);
    qq += __shfl_xor(qq, mask);
  }
  float mu = s * (1.f / CH);
  float var = qq * (1.f / CH) - mu * mu;
  float rs = rsqrtf(fmaxf(var, 0.f) + LN_EPS);
  F4 uw = *(const F4*)(w + lane * 4);
  F4 ub = *(const F4*)(b + lane * 4);
  US4 o;
  o.x = f2bf((v0 - mu) * rs * uw.x + ub.x);
  o.y = f2bf((v1 - mu) * rs * uw.y + ub.y);
  o.z = f2bf((v2 - mu) * rs * uw.z + ub.z);
  o.w = f2bf((v3 - mu) * rs * uw.w + ub.w);
  *(US4*)(x4ln + row * CH + lane * 4) = o;
}

// ---------------------------------------------------------------------------
// Final: out[b][c][pos] = x3[b][pos][c] + x4[b][pos][c]  (fp32 out)
// ---------------------------------------------------------------------------
__global__ __launch_bounds__(256) void k_add_t(const u16* __restrict__ x3,
                                               const u16* __restrict__ x4,
                                               float* __restrict__ out) {
  __shared__ float tl[64][66];
  const int t = threadIdx.x;
  const int bb = blockIdx.x >> 6;
  const int pb = (blockIdx.x >> 2) & 15, cb = blockIdx.x & 3;
  const int pos0 = pb * 64, c0 = cb * 64;
#pragma unroll
  for (int it = 0; it < 16; ++it) {
    int c_l = t & 63, p_l = it * 4 + (t >> 6);
    size_t ro = ((size_t)bb * NT + pos0 + p_l) * CH + c0 + c_l;
    tl[p_l][c_l] = bf2f(x3[ro]) + bf2f(x4[ro]);
  }
  __syncthreads();
#pragma unroll
  for (int it = 0; it < 16; ++it) {
    int p_l = t & 63, c_l = it * 4 + (t >> 6);
    out[((size_t)bb * CH + c0 + c_l) * NT + pos0 + p_l] = tl[p_l][c_l];
  }
}

// ---------------------------------------------------------------------------
// Launch
// ---------------------------------------------------------------------------
extern "C" void kernel_launch(void* const* d_in, const int* in_sizes, int n_in,
                              void* d_out, int out_size, void* d_ws, size_t ws_size,
                              hipStream_t stream) {
  const float* x       = (const float*)d_in[0];
  const float* qkv_w   = (const float*)d_in[1];
  const float* proj_w  = (const float*)d_in[2];
  const float* proj_b  = (const float*)d_in[3];
  const float* ffn_w1  = (const float*)d_in[4];
  const float* ffn_b1  = (const float*)d_in[5];
  const float* ffn_w2  = (const float*)d_in[6];
  const float* ffn_b2  = (const float*)d_in[7];
  const float* norm1_w = (const float*)d_in[8];
  const float* norm1_b = (const float*)d_in[9];
  const float* norm2_w = (const float*)d_in[10];
  const float* norm2_b = (const float*)d_in[11];
  const float* btab    = (const float*)d_in[12];
  const int* rel       = (const int*)d_in[13];
  float* out = (float*)d_out;

  char* ws = (char*)d_ws;
  size_t off = 0;
  auto alloc = [&](size_t bytes) { char* p = ws + off; off += bytes; return p; };
  u16* qkv_wT  = (u16*)alloc((size_t)768 * 256 * 2);
  u16* proj_wT = (u16*)alloc((size_t)256 * 256 * 2);
  u16* w1T     = (u16*)alloc((size_t)1024 * 256 * 2);
  u16* w2T     = (u16*)alloc((size_t)256 * 1024 * 2);
  u16* biasL   = (u16*)alloc((size_t)NH * NT * NT * 2);   // 16.78 MB
  u16* qm      = (u16*)alloc((size_t)MROWS * CH * 2);     // 8.39 MB
  u16* km      = (u16*)alloc((size_t)MROWS * CH * 2);     // 8.39 MB
  u16* vm      = (u16*)alloc((size_t)MROWS * CH * 2);     // 8.39 MB (as vT)
  u16* bufX    = (u16*)alloc((size_t)MROWS * CH * 2);     // 8.39 MB
  u16* x3      = (u16*)alloc((size_t)MROWS * CH * 2);     // 8.39 MB
  u16* ffn_h = biasL;  // overlay (dead after attention)
  u16* x4ln  = vm;     // overlay (dead after attention)
  u16* x1 = bufX;
  u16* ao = bufX;
  u16* x4 = bufX;
  (void)ws_size; (void)in_sizes; (void)n_in; (void)out_size;

  k_transpose<<<dim3(4, 12), 256, 0, stream>>>(qkv_w, qkv_wT, 256, 768);
  k_transpose<<<dim3(4, 4), 256, 0, stream>>>(proj_w, proj_wT, 256, 256);
  k_transpose<<<dim3(4, 16), 256, 0, stream>>>(ffn_w1, w1T, 256, 1024);
  k_transpose<<<dim3(16, 4), 256, 0, stream>>>(ffn_w2, w2T, 1024, 256);
  k_prep_bias<<<256, 256, 0, stream>>>(btab, rel, biasL);
  k_ln1<<<BATCH * 16, 256, 0, stream>>>(x, norm1_w, norm1_b, x1);
  k_gemm_qkv<<<dim3(MROWS / 128, 6), 256, 0, stream>>>(x1, qkv_wT, qm, km, vm);
  k_attn<<<BATCH * NH * 16, 256, 0, stream>>>(qm, km, vm, biasL, ao);
  k_gemm_proj<<<dim3(MROWS / 128, 2), 256, 0, stream>>>(ao, proj_wT, proj_b, x, x3);
  k_ln2<<<MROWS / 4, 256, 0, stream>>>(x3, norm2_w, norm2_b, x4ln);
  k_gemm_ffn1<<<dim3(MROWS / 128, 8), 256, 0, stream>>>(x4ln, w1T, ffn_b1, ffn_h);
  k_gemm_ffn2<<<dim3(MROWS / 128, 2), 256, 0, stream>>>(ffn_h, w2T, ffn_b2, x4);
  k_add_t<<<BATCH * 16 * 4, 256, 0, stream>>>(x3, x4, out);
}